// Round 1
// baseline (6560.635 us; speedup 1.0000x reference)
//
#include <hip/hip_runtime.h>

#define Bsz 2
#define Tsz 2048
#define Csz 1024
#define Hsz 16
#define Dsz 64
#define BT (Bsz*Tsz)   // 4096

typedef unsigned short u16;
typedef __attribute__((ext_vector_type(8))) short bf16x8_t;
typedef __attribute__((ext_vector_type(4))) float f32x4;
typedef __attribute__((ext_vector_type(4))) unsigned short us4;

__device__ __forceinline__ float bf2f(u16 u){
    union { unsigned i; float f; } c; c.i = ((unsigned)u) << 16; return c.f;
}
__device__ __forceinline__ u16 f2bf(float f){
    union { float f; unsigned i; } c; c.f = f;
    unsigned i = c.i;
    unsigned r = (i + 0x7fffu + ((i >> 16) & 1u)) >> 16;
    return (u16)r;
}

// ---------------------------------------------------------------- rope tables
// ctab/stab: [T][16], entry m corresponds to freq index i = 2m of the reference
__global__ void rope_tables_k(float* __restrict__ ctab, float* __restrict__ stab){
    int idx = blockIdx.x * blockDim.x + threadIdx.x;
    if (idx >= Tsz * 16) return;
    int t = idx >> 4, m = idx & 15;
    float arf = (float)m / 16.f;                   // ar[i]=i/32, i=2m
    double sb = 10000.0 * pow(32.0, 64.0 / 62.0);  // scaled_base
    float invf = (float)(1.0 / pow(sb, (double)arf));
    float fe   = (float)(1.0 / pow(10000.0, (double)arf));
    float wl   = 6.283185307179586f / fe;
    float ms   = fminf(fmaxf((wl - 1.0f) / 31.0f, 0.f), 1.f);
    float scale = 1.f + 31.f * ms;
    float freq = ((float)t / scale) * invf;
    ctab[idx] = cosf(freq);
    stab[idx] = sinf(freq);
}

// ---------------------------------------------------------------- f32 -> bf16
__global__ void cvt_f32_bf16_k(const float* __restrict__ in, u16* __restrict__ out, int n){
    int i = (blockIdx.x * blockDim.x + threadIdx.x) * 4;
    if (i >= n) return;
    float4 v = *(const float4*)(in + i);
    us4 o; o.x = f2bf(v.x); o.y = f2bf(v.y); o.z = f2bf(v.z); o.w = f2bf(v.w);
    *(us4*)(out + i) = o;
}

// ---------------------------------------------------------------- bf16 MFMA GEMM
// C[m][n] = sum_k A[m][k] * Bw[n][k]   (A: MxK row-major, Bw: NxK row-major)
// writes f32 to Cf if non-null, else bf16 to Cb.
__global__ __launch_bounds__(256) void gemm_bf16_nt(
    const u16* __restrict__ A, const u16* __restrict__ Bw,
    float* __restrict__ Cf, u16* __restrict__ Cb,
    int M, int N, int Kdim)
{
    const int l  = threadIdx.x & 63;
    const int w  = threadIdx.x >> 6;
    const int wm = (w >> 1) << 6;
    const int wn = (w & 1) << 6;
    const int lm = l & 15;
    const int lg = l >> 4;
    const long arow = (long)blockIdx.x * 128 + wm + lm;
    const long brow = (long)blockIdx.y * 128 + wn + lm;
    const u16* Ap = A + arow * Kdim + lg * 8;
    const u16* Bp = Bw + brow * Kdim + lg * 8;

    f32x4 acc[4][4];
#pragma unroll
    for (int i = 0; i < 4; i++)
#pragma unroll
        for (int j = 0; j < 4; j++) acc[i][j] = (f32x4){0.f, 0.f, 0.f, 0.f};

    for (int k0 = 0; k0 < Kdim; k0 += 32) {
        bf16x8_t av[4], bv[4];
#pragma unroll
        for (int i = 0; i < 4; i++) av[i] = *(const bf16x8_t*)(Ap + (long)i * 16 * Kdim + k0);
#pragma unroll
        for (int j = 0; j < 4; j++) bv[j] = *(const bf16x8_t*)(Bp + (long)j * 16 * Kdim + k0);
#pragma unroll
        for (int i = 0; i < 4; i++)
#pragma unroll
            for (int j = 0; j < 4; j++)
                acc[i][j] = __builtin_amdgcn_mfma_f32_16x16x32_bf16(av[i], bv[j], acc[i][j], 0, 0, 0);
    }

    const int crow0 = blockIdx.x * 128 + wm + lg * 4;  // C/D: row=(lane>>4)*4+r, col=lane&15
    const int ccol0 = blockIdx.y * 128 + wn + lm;
#pragma unroll
    for (int i = 0; i < 4; i++)
#pragma unroll
        for (int j = 0; j < 4; j++)
#pragma unroll
            for (int r = 0; r < 4; r++) {
                long row = crow0 + i * 16 + r;
                long col = ccol0 + j * 16;
                float vv = acc[i][j][r];
                if (Cf) Cf[row * N + col] = vv;
                else    Cb[row * N + col] = f2bf(vv);
            }
}

// ---------------------------------------------------------------- depthwise conv K=4 + silu
// pre: bf16 (B,T,C); out: f32 (B,T,C).  out[t] = silu(b + sum_j w[j]*pre[t-3+j])
__global__ __launch_bounds__(256) void conv_silu_k(
    const u16* __restrict__ pre, const float* __restrict__ w,
    const float* __restrict__ bias, float* __restrict__ out)
{
    int c  = blockIdx.y * 256 + threadIdx.x;
    int bi = blockIdx.x;              // B * (T/64)
    int b  = bi >> 5;
    int t0 = (bi & 31) << 6;
    float w0 = w[c*4+0], w1 = w[c*4+1], w2 = w[c*4+2], w3 = w[c*4+3];
    float bs = bias[c];
    long base = ((long)b * Tsz) * Csz + c;
    float xm3 = (t0 >= 3) ? bf2f(pre[base + (long)(t0-3)*Csz]) : 0.f;
    float xm2 = (t0 >= 2) ? bf2f(pre[base + (long)(t0-2)*Csz]) : 0.f;
    float xm1 = (t0 >= 1) ? bf2f(pre[base + (long)(t0-1)*Csz]) : 0.f;
    for (int t = t0; t < t0 + 64; t++) {
        float xc = bf2f(pre[base + (long)t * Csz]);
        float z  = bs + w0*xm3 + w1*xm2 + w2*xm1 + w3*xc;
        out[base + (long)t * Csz] = z / (1.f + expf(-z));
        xm3 = xm2; xm2 = xm1; xm1 = xc;
    }
}

// ---------------------------------------------------------------- rope + l2norm (in-place, f32)
// one wave per (b,t,h) row of 64
__global__ __launch_bounds__(256) void rope_l2norm_k(
    float* __restrict__ qk, const float* __restrict__ ctab, const float* __restrict__ stab)
{
    int row = blockIdx.x * 4 + (threadIdx.x >> 6);
    int j   = threadIdx.x & 63;
    int t   = (row >> 4) & (Tsz - 1);
    int p   = j & 31, m = j & 15, hi = j >> 5;
    float2 xv = *(const float2*)(qk + (long)row * 64 + p * 2);
    float c = ctab[t * 16 + m], s = stab[t * 16 + m];
    float val = hi ? (xv.x * s + xv.y * c) : (xv.x * c - xv.y * s);
    float ss = val * val;
#pragma unroll
    for (int off = 1; off < 64; off <<= 1) ss += __shfl_xor(ss, off);
    float inv = 1.f / fmaxf(sqrtf(ss), 1e-12f);
    qk[(long)row * 64 + j] = val * inv;
}

// ---------------------------------------------------------------- beta / alpha
__global__ __launch_bounds__(256) void ab_k(
    const float* __restrict__ x,
    const float* __restrict__ Wb,  const float* __restrict__ bb,
    const float* __restrict__ Wgk, const float* __restrict__ bgk,
    const float* __restrict__ A_log, const float* __restrict__ dtb,
    float* __restrict__ alpha, float* __restrict__ beta)
{
    __shared__ float xr[1024];
    int bt = blockIdx.x;
    const float* xp = x + (long)bt * 1024;
#pragma unroll
    for (int i = 0; i < 4; i++) xr[threadIdx.x + i * 256] = xp[threadIdx.x + i * 256];
    __syncthreads();
    int wv = threadIdx.x >> 6, l = threadIdx.x & 63;
#pragma unroll
    for (int oo = 0; oo < 8; oo++) {
        int o = wv * 8 + oo;           // 0..15: beta, 16..31: alpha
        int h = o & 15;
        const float* wr = (o < 16 ? Wb : Wgk) + (long)h * 1024;
        float p = 0.f;
#pragma unroll
        for (int i = 0; i < 16; i++) p += wr[l + i * 64] * xr[l + i * 64];
        for (int off = 32; off; off >>= 1) p += __shfl_xor(p, off);
        if (l == 0) {
            if (o < 16) {
                beta[bt * 16 + h] = 1.f / (1.f + expf(-(p + bb[h])));
            } else {
                float gk = p + bgk[h] + dtb[h];
                float sp = gk > 0.f ? gk + log1pf(expf(-gk)) : log1pf(expf(gk));
                alpha[bt * 16 + h] = expf(-expf(A_log[h]) * sp);
            }
        }
    }
}

// ---------------------------------------------------------------- delta-rule recurrence
// 1 wave per (b,h); lane = v-row; S[64] in VGPRs. Fused D-skip + rmsnorm + silu + gate.
__global__ __launch_bounds__(64, 1) void recur_k(
    const float* __restrict__ q, const float* __restrict__ k, const float* __restrict__ v,
    const float* __restrict__ alpha, const float* __restrict__ beta,
    const u16* __restrict__ g, const float* __restrict__ Dp,
    const float* __restrict__ onw, u16* __restrict__ oact)
{
    int b = blockIdx.x >> 4, h = blockIdx.x & 15;
    int lane = threadIdx.x;
    float S[64];
#pragma unroll
    for (int i = 0; i < 64; i++) S[i] = 0.f;
    float dp = Dp[h], wn = onw[lane];

    for (int t = 0; t < Tsz; t++) {
        long base = (((long)b * Tsz + t) * Hsz + h) * 64;
        float vt = v[base + lane];
        float gt = bf2f(g[base + lane]);
        float at = alpha[(b * Tsz + t) * Hsz + h];
        float bt = beta [(b * Tsz + t) * Hsz + h];
        float kr[64], qr[64];
        const float4* k4 = (const float4*)(k + base);
        const float4* q4 = (const float4*)(q + base);
#pragma unroll
        for (int i = 0; i < 16; i++) {
            float4 kv = k4[i]; kr[4*i] = kv.x; kr[4*i+1] = kv.y; kr[4*i+2] = kv.z; kr[4*i+3] = kv.w;
            float4 qv = q4[i]; qr[4*i] = qv.x; qr[4*i+1] = qv.y; qr[4*i+2] = qv.z; qr[4*i+3] = qv.w;
        }
        float s0 = 0, s1 = 0, s2 = 0, s3 = 0;
#pragma unroll
        for (int i = 0; i < 16; i++) {
            s0 += S[4*i]   * kr[4*i];
            s1 += S[4*i+1] * kr[4*i+1];
            s2 += S[4*i+2] * kr[4*i+2];
            s3 += S[4*i+3] * kr[4*i+3];
        }
        float sk = (s0 + s1) + (s2 + s3);
        float cc = bt * (vt - at * sk);
        float o0 = 0, o1 = 0, o2 = 0, o3 = 0;
#pragma unroll
        for (int i = 0; i < 16; i++) {
            S[4*i]   = at * S[4*i]   + cc * kr[4*i];   o0 += S[4*i]   * qr[4*i];
            S[4*i+1] = at * S[4*i+1] + cc * kr[4*i+1]; o1 += S[4*i+1] * qr[4*i+1];
            S[4*i+2] = at * S[4*i+2] + cc * kr[4*i+2]; o2 += S[4*i+2] * qr[4*i+2];
            S[4*i+3] = at * S[4*i+3] + cc * kr[4*i+3]; o3 += S[4*i+3] * qr[4*i+3];
        }
        float o = (o0 + o1) + (o2 + o3) + dp * vt;
        float ss = o * o;
#pragma unroll
        for (int off = 1; off < 64; off <<= 1) ss += __shfl_xor(ss, off);
        float r   = rsqrtf(ss * (1.f / 64.f) + 1e-6f);
        float on  = wn * (o * r);
        float sil = on / (1.f + expf(-on));
        oact[base + lane] = f2bf(gt * sil);
    }
}

// ---------------------------------------------------------------- host launch
extern "C" void kernel_launch(void* const* d_in, const int* in_sizes, int n_in,
                              void* d_out, int out_size, void* d_ws, size_t ws_size,
                              hipStream_t stream)
{
    const float* x    = (const float*)d_in[0];
    const float* Wq   = (const float*)d_in[1];
    const float* Wk   = (const float*)d_in[2];
    const float* Wv   = (const float*)d_in[3];
    const float* Wg   = (const float*)d_in[4];
    const float* Wo   = (const float*)d_in[5];
    const float* Wb   = (const float*)d_in[6];
    const float* bb   = (const float*)d_in[7];
    const float* Wgk  = (const float*)d_in[8];
    const float* bgk  = (const float*)d_in[9];
    const float* cqw  = (const float*)d_in[10];
    const float* cqb  = (const float*)d_in[11];
    const float* ckw  = (const float*)d_in[12];
    const float* ckb  = (const float*)d_in[13];
    const float* cvw  = (const float*)d_in[14];
    const float* cvb  = (const float*)d_in[15];
    const float* A_log= (const float*)d_in[16];
    const float* Dp   = (const float*)d_in[17];
    const float* dtb  = (const float*)d_in[18];
    const float* onw  = (const float*)d_in[19];
    float* out = (float*)d_out;

    char* p = (char*)d_ws;
    auto alloc = [&](size_t bytes) -> char* {
        char* r = p; p += (bytes + 255) & ~(size_t)255; return r;
    };
    const size_t NBT = (size_t)BT * Csz;          // 4M elements
    u16*   xbf   = (u16*)  alloc(NBT * 2);
    u16*   Wqbf  = (u16*)  alloc((size_t)Csz * Csz * 2);
    u16*   Wkbf  = (u16*)  alloc((size_t)Csz * Csz * 2);
    u16*   Wvbf  = (u16*)  alloc((size_t)Csz * Csz * 2);
    u16*   Wgbf  = (u16*)  alloc((size_t)Csz * Csz * 2);
    u16*   Wobf  = (u16*)  alloc((size_t)Csz * Csz * 2);
    u16*   qpre  = (u16*)  alloc(NBT * 2);
    u16*   kpre  = (u16*)  alloc(NBT * 2);        // contiguous with qpre
    u16*   vpre  = (u16*)  alloc(NBT * 2);
    u16*   gbf   = (u16*)  alloc(NBT * 2);
    float* qconv = (float*)alloc(NBT * 4);
    float* kconv = (float*)alloc(NBT * 4);
    float* ctab  = (float*)alloc((size_t)Tsz * 16 * 4);
    float* stab  = (float*)alloc((size_t)Tsz * 16 * 4);
    float* alpha = (float*)alloc((size_t)BT * Hsz * 4);
    float* beta  = (float*)alloc((size_t)BT * Hsz * 4);
    // overlays (stream-ordered reuse of dead buffers):
    float* vconv = (float*)qpre;   // 16MB over qpre+kpre (dead after conv_q/conv_k)
    u16*   oact  = (u16*)vpre;     // 8MB over vpre (dead after conv_v)

    // 1. rope tables
    rope_tables_k<<<(Tsz * 16 + 255) / 256, 256, 0, stream>>>(ctab, stab);

    // 2. f32 -> bf16 conversions
    cvt_f32_bf16_k<<<(int)(NBT / 4 + 255) / 256, 256, 0, stream>>>(x,  xbf,  (int)NBT);
    cvt_f32_bf16_k<<<(Csz * Csz / 4 + 255) / 256, 256, 0, stream>>>(Wq, Wqbf, Csz * Csz);
    cvt_f32_bf16_k<<<(Csz * Csz / 4 + 255) / 256, 256, 0, stream>>>(Wk, Wkbf, Csz * Csz);
    cvt_f32_bf16_k<<<(Csz * Csz / 4 + 255) / 256, 256, 0, stream>>>(Wv, Wvbf, Csz * Csz);
    cvt_f32_bf16_k<<<(Csz * Csz / 4 + 255) / 256, 256, 0, stream>>>(Wg, Wgbf, Csz * Csz);
    cvt_f32_bf16_k<<<(Csz * Csz / 4 + 255) / 256, 256, 0, stream>>>(Wo, Wobf, Csz * Csz);

    // 3. projections (bf16 out)
    dim3 ggrid(BT / 128, Csz / 128);
    gemm_bf16_nt<<<ggrid, 256, 0, stream>>>(xbf, Wqbf, nullptr, qpre, BT, Csz, Csz);
    gemm_bf16_nt<<<ggrid, 256, 0, stream>>>(xbf, Wkbf, nullptr, kpre, BT, Csz, Csz);
    gemm_bf16_nt<<<ggrid, 256, 0, stream>>>(xbf, Wvbf, nullptr, vpre, BT, Csz, Csz);
    gemm_bf16_nt<<<ggrid, 256, 0, stream>>>(xbf, Wgbf, nullptr, gbf,  BT, Csz, Csz);

    // 4. depthwise conv + silu (f32 out)
    dim3 cgrid(Bsz * (Tsz / 64), Csz / 256);
    conv_silu_k<<<cgrid, 256, 0, stream>>>(qpre, cqw, cqb, qconv);
    conv_silu_k<<<cgrid, 256, 0, stream>>>(kpre, ckw, ckb, kconv);
    conv_silu_k<<<cgrid, 256, 0, stream>>>(vpre, cvw, cvb, vconv);

    // 5. rope + l2norm, in place on q/k
    rope_l2norm_k<<<(Bsz * Tsz * Hsz) / 4, 256, 0, stream>>>(qconv, ctab, stab);
    rope_l2norm_k<<<(Bsz * Tsz * Hsz) / 4, 256, 0, stream>>>(kconv, ctab, stab);

    // 6. beta / alpha
    ab_k<<<BT, 256, 0, stream>>>(x, Wb, bb, Wgk, bgk, A_log, dtb, alpha, beta);

    // 7. recurrence + fused epilogue (bf16 o_act)
    recur_k<<<Bsz * Hsz, 64, 0, stream>>>(qconv, kconv, vconv, alpha, beta,
                                          gbf, Dp, onw, oact);

    // 8. output projection (f32 -> d_out)
    gemm_bf16_nt<<<ggrid, 256, 0, stream>>>(oact, Wobf, out, nullptr, BT, Csz, Csz);

    (void)in_sizes; (void)n_in; (void)out_size; (void)ws_size;
}

// Round 2
// 2090.626 us; speedup vs baseline: 3.1381x; 3.1381x over previous
//
#include <hip/hip_runtime.h>

#define Bsz 2
#define Tsz 2048
#define Csz 1024
#define Hsz 16
#define Dsz 64
#define BT (Bsz*Tsz)   // 4096

typedef unsigned short u16;
typedef __attribute__((ext_vector_type(8))) short bf16x8_t;
typedef __attribute__((ext_vector_type(4))) float f32x4;
typedef __attribute__((ext_vector_type(4))) unsigned short us4;

__device__ __forceinline__ float bf2f(u16 u){
    union { unsigned i; float f; } c; c.i = ((unsigned)u) << 16; return c.f;
}
__device__ __forceinline__ u16 f2bf(float f){
    union { float f; unsigned i; } c; c.f = f;
    unsigned i = c.i;
    unsigned r = (i + 0x7fffu + ((i >> 16) & 1u)) >> 16;
    return (u16)r;
}

// ---------------------------------------------------------------- rope tables
__global__ void rope_tables_k(float* __restrict__ ctab, float* __restrict__ stab){
    int idx = blockIdx.x * blockDim.x + threadIdx.x;
    if (idx >= Tsz * 16) return;
    int t = idx >> 4, m = idx & 15;
    float arf = (float)m / 16.f;                   // ar[i]=i/32, i=2m
    double sb = 10000.0 * pow(32.0, 64.0 / 62.0);  // scaled_base
    float invf = (float)(1.0 / pow(sb, (double)arf));
    float fe   = (float)(1.0 / pow(10000.0, (double)arf));
    float wl   = 6.283185307179586f / fe;
    float ms   = fminf(fmaxf((wl - 1.0f) / 31.0f, 0.f), 1.f);
    float scale = 1.f + 31.f * ms;
    float freq = ((float)t / scale) * invf;
    ctab[idx] = cosf(freq);
    stab[idx] = sinf(freq);
}

// ---------------------------------------------------------------- f32 -> bf16
__global__ void cvt_f32_bf16_k(const float* __restrict__ in, u16* __restrict__ out, int n){
    int i = (blockIdx.x * blockDim.x + threadIdx.x) * 4;
    if (i >= n) return;
    float4 v = *(const float4*)(in + i);
    us4 o; o.x = f2bf(v.x); o.y = f2bf(v.y); o.z = f2bf(v.z); o.w = f2bf(v.w);
    *(us4*)(out + i) = o;
}

// ---------------------------------------------------------------- bf16 MFMA GEMM
__global__ __launch_bounds__(256) void gemm_bf16_nt(
    const u16* __restrict__ A, const u16* __restrict__ Bw,
    float* __restrict__ Cf, u16* __restrict__ Cb,
    int M, int N, int Kdim)
{
    const int l  = threadIdx.x & 63;
    const int w  = threadIdx.x >> 6;
    const int wm = (w >> 1) << 6;
    const int wn = (w & 1) << 6;
    const int lm = l & 15;
    const int lg = l >> 4;
    const long arow = (long)blockIdx.x * 128 + wm + lm;
    const long brow = (long)blockIdx.y * 128 + wn + lm;
    const u16* Ap = A + arow * Kdim + lg * 8;
    const u16* Bp = Bw + brow * Kdim + lg * 8;

    f32x4 acc[4][4];
#pragma unroll
    for (int i = 0; i < 4; i++)
#pragma unroll
        for (int j = 0; j < 4; j++) acc[i][j] = (f32x4){0.f, 0.f, 0.f, 0.f};

    for (int k0 = 0; k0 < Kdim; k0 += 32) {
        bf16x8_t av[4], bv[4];
#pragma unroll
        for (int i = 0; i < 4; i++) av[i] = *(const bf16x8_t*)(Ap + (long)i * 16 * Kdim + k0);
#pragma unroll
        for (int j = 0; j < 4; j++) bv[j] = *(const bf16x8_t*)(Bp + (long)j * 16 * Kdim + k0);
#pragma unroll
        for (int i = 0; i < 4; i++)
#pragma unroll
            for (int j = 0; j < 4; j++)
                acc[i][j] = __builtin_amdgcn_mfma_f32_16x16x32_bf16(av[i], bv[j], acc[i][j], 0, 0, 0);
    }

    const int crow0 = blockIdx.x * 128 + wm + lg * 4;
    const int ccol0 = blockIdx.y * 128 + wn + lm;
#pragma unroll
    for (int i = 0; i < 4; i++)
#pragma unroll
        for (int j = 0; j < 4; j++)
#pragma unroll
            for (int r = 0; r < 4; r++) {
                long row = crow0 + i * 16 + r;
                long col = ccol0 + j * 16;
                float vv = acc[i][j][r];
                if (Cf) Cf[row * N + col] = vv;
                else    Cb[row * N + col] = f2bf(vv);
            }
}

// ---------------------------------------------------------------- depthwise conv K=4 + silu
__global__ __launch_bounds__(256) void conv_silu_k(
    const u16* __restrict__ pre, const float* __restrict__ w,
    const float* __restrict__ bias, float* __restrict__ out)
{
    int c  = blockIdx.y * 256 + threadIdx.x;
    int bi = blockIdx.x;              // B * (T/64)
    int b  = bi >> 5;
    int t0 = (bi & 31) << 6;
    float w0 = w[c*4+0], w1 = w[c*4+1], w2 = w[c*4+2], w3 = w[c*4+3];
    float bs = bias[c];
    long base = ((long)b * Tsz) * Csz + c;
    float xm3 = (t0 >= 3) ? bf2f(pre[base + (long)(t0-3)*Csz]) : 0.f;
    float xm2 = (t0 >= 2) ? bf2f(pre[base + (long)(t0-2)*Csz]) : 0.f;
    float xm1 = (t0 >= 1) ? bf2f(pre[base + (long)(t0-1)*Csz]) : 0.f;
    for (int t = t0; t < t0 + 64; t++) {
        float xc = bf2f(pre[base + (long)t * Csz]);
        float z  = bs + w0*xm3 + w1*xm2 + w2*xm1 + w3*xc;
        out[base + (long)t * Csz] = z / (1.f + expf(-z));
        xm3 = xm2; xm2 = xm1; xm1 = xc;
    }
}

// ---------------------------------------------------------------- rope + l2norm (in-place, f32)
__global__ __launch_bounds__(256) void rope_l2norm_k(
    float* __restrict__ qk, const float* __restrict__ ctab, const float* __restrict__ stab)
{
    int row = blockIdx.x * 4 + (threadIdx.x >> 6);
    int j   = threadIdx.x & 63;
    int t   = (row >> 4) & (Tsz - 1);
    int p   = j & 31, m = j & 15, hi = j >> 5;
    float2 xv = *(const float2*)(qk + (long)row * 64 + p * 2);
    float c = ctab[t * 16 + m], s = stab[t * 16 + m];
    float val = hi ? (xv.x * s + xv.y * c) : (xv.x * c - xv.y * s);
    float ss = val * val;
#pragma unroll
    for (int off = 1; off < 64; off <<= 1) ss += __shfl_xor(ss, off);
    float inv = 1.f / fmaxf(sqrtf(ss), 1e-12f);
    qk[(long)row * 64 + j] = val * inv;
}

// ---------------------------------------------------------------- beta / alpha
__global__ __launch_bounds__(256) void ab_k(
    const float* __restrict__ x,
    const float* __restrict__ Wb,  const float* __restrict__ bb,
    const float* __restrict__ Wgk, const float* __restrict__ bgk,
    const float* __restrict__ A_log, const float* __restrict__ dtb,
    float* __restrict__ alpha, float* __restrict__ beta)
{
    __shared__ float xr[1024];
    int bt = blockIdx.x;
    const float* xp = x + (long)bt * 1024;
#pragma unroll
    for (int i = 0; i < 4; i++) xr[threadIdx.x + i * 256] = xp[threadIdx.x + i * 256];
    __syncthreads();
    int wv = threadIdx.x >> 6, l = threadIdx.x & 63;
#pragma unroll
    for (int oo = 0; oo < 8; oo++) {
        int o = wv * 8 + oo;           // 0..15: beta, 16..31: alpha
        int h = o & 15;
        const float* wr = (o < 16 ? Wb : Wgk) + (long)h * 1024;
        float p = 0.f;
#pragma unroll
        for (int i = 0; i < 16; i++) p += wr[l + i * 64] * xr[l + i * 64];
        for (int off = 32; off; off >>= 1) p += __shfl_xor(p, off);
        if (l == 0) {
            if (o < 16) {
                beta[bt * 16 + h] = 1.f / (1.f + expf(-(p + bb[h])));
            } else {
                float gk = p + bgk[h] + dtb[h];
                float sp = gk > 0.f ? gk + log1pf(expf(-gk)) : log1pf(expf(gk));
                alpha[bt * 16 + h] = expf(-expf(A_log[h]) * sp);
            }
        }
    }
}

// ---------------------------------------------------------------- delta-rule recurrence
// 1 wave per (b,h); lane = v-row. State + double-buffered q/k rows in NAMED registers
// (SROA-proof). Loads for step t+1 are issued before compute of step t.
#define F16A(X)      X(0) X(1) X(2) X(3) X(4) X(5) X(6) X(7) X(8) X(9) X(10) X(11) X(12) X(13) X(14) X(15)
#define F16B(X,A)    X(0,A) X(1,A) X(2,A) X(3,A) X(4,A) X(5,A) X(6,A) X(7,A) X(8,A) X(9,A) X(10,A) X(11,A) X(12,A) X(13,A) X(14,A) X(15,A)
#define F16C(X,A,B)  X(0,A,B) X(1,A,B) X(2,A,B) X(3,A,B) X(4,A,B) X(5,A,B) X(6,A,B) X(7,A,B) X(8,A,B) X(9,A,B) X(10,A,B) X(11,A,B) X(12,A,B) X(13,A,B) X(14,A,B) X(15,A,B)

#define DECLS(i) f32x4 S##i = {0.f,0.f,0.f,0.f};
#define DECLB(i) float4 ka##i, qa##i, kb##i, qb##i;
#define LD1(i,KP,QP) KP##i = kv4[i]; QP##i = qv4[i];
#define SK1(i,KP) sk0 += S##i.x * KP##i.x; sk1 += S##i.y * KP##i.y; sk2 += S##i.z * KP##i.z; sk3 += S##i.w * KP##i.w;
#define UP1(i,KP,QP) \
    S##i.x = at_*S##i.x + cc_*KP##i.x; o0 += S##i.x * QP##i.x; \
    S##i.y = at_*S##i.y + cc_*KP##i.y; o1 += S##i.y * QP##i.y; \
    S##i.z = at_*S##i.z + cc_*KP##i.z; o2 += S##i.z * QP##i.z; \
    S##i.w = at_*S##i.w + cc_*KP##i.w; o3 += S##i.w * QP##i.w;

#define LOADSET(KP,QP,VV,AA,BB,TT) do { \
    long r_ = ((long)b * Tsz + (TT)) * Hsz + h; \
    const float4* kv4 = (const float4*)(kz + (r_ << 6)); \
    const float4* qv4 = (const float4*)(qz + (r_ << 6)); \
    F16C(LD1,KP,QP) \
    VV = v[(r_ << 6) + lane]; \
    AA = alpha[r_]; BB = beta[r_]; \
} while(0)

#define STEP(KP,QP,VV,AA,BB,TT) do { \
    float at_ = AA, bt_ = BB; \
    float sk0=0.f, sk1=0.f, sk2=0.f, sk3=0.f; \
    F16B(SK1,KP) \
    float cc_ = bt_ * (VV - at_ * ((sk0+sk1)+(sk2+sk3))); \
    float o0=0.f, o1=0.f, o2=0.f, o3=0.f; \
    F16C(UP1,KP,QP) \
    float oo_ = (o0+o1)+(o2+o3) + dp*VV; \
    oact[((((long)b * Tsz + (TT)) * Hsz + h) << 6) + lane] = f2bf(oo_); \
} while(0)

__global__ __launch_bounds__(64, 1) void recur_k(
    const float* __restrict__ q, const float* __restrict__ k, const float* __restrict__ v,
    const float* __restrict__ alpha, const float* __restrict__ beta,
    const float* __restrict__ Dp, u16* __restrict__ oact)
{
    const int b = blockIdx.x >> 4, h = blockIdx.x & 15;
    const int lane = threadIdx.x;
    const float dp = Dp[h];
    // z is 0 for all lanes but statically opaque -> forces VGPR (vector) loads,
    // preventing the SGPR-scalarization pathology seen in round 1 (VGPR_Count=44).
    const int z = (int)(threadIdx.x >> 6);
    const float* kz = k + ((long)z << 6);
    const float* qz = q + ((long)z << 6);

    F16A(DECLS)
    F16A(DECLB)
    float va_, aa_, ba_, vb_, ab2_, bb2_;

    LOADSET(ka, qa, va_, aa_, ba_, 0);
    for (int t = 0; t < Tsz; t += 2) {
        LOADSET(kb, qb, vb_, ab2_, bb2_, t + 1);
        STEP(ka, qa, va_, aa_, ba_, t);
        if (t + 2 < Tsz) LOADSET(ka, qa, va_, aa_, ba_, t + 2);
        STEP(kb, qb, vb_, ab2_, bb2_, t + 1);
    }
}

// ---------------------------------------------------------------- epilogue: rmsnorm+silu+gate
// in-place on o (bf16); one wave per (b,t,h) row
__global__ __launch_bounds__(256) void epi_k(
    u16* __restrict__ o, const u16* __restrict__ g, const float* __restrict__ onw)
{
    long row = blockIdx.x * 4 + (threadIdx.x >> 6);
    int lane = threadIdx.x & 63;
    long idx = (row << 6) + lane;
    float ov = bf2f(o[idx]);
    float gv = bf2f(g[idx]);
    float ss = ov * ov;
#pragma unroll
    for (int off = 1; off < 64; off <<= 1) ss += __shfl_xor(ss, off);
    float r   = rsqrtf(ss * (1.f / 64.f) + 1e-6f);
    float on  = onw[lane] * (ov * r);
    float sil = on / (1.f + expf(-on));
    o[idx] = f2bf(gv * sil);
}

// ---------------------------------------------------------------- host launch
extern "C" void kernel_launch(void* const* d_in, const int* in_sizes, int n_in,
                              void* d_out, int out_size, void* d_ws, size_t ws_size,
                              hipStream_t stream)
{
    const float* x    = (const float*)d_in[0];
    const float* Wq   = (const float*)d_in[1];
    const float* Wk   = (const float*)d_in[2];
    const float* Wv   = (const float*)d_in[3];
    const float* Wg   = (const float*)d_in[4];
    const float* Wo   = (const float*)d_in[5];
    const float* Wb   = (const float*)d_in[6];
    const float* bb   = (const float*)d_in[7];
    const float* Wgk  = (const float*)d_in[8];
    const float* bgk  = (const float*)d_in[9];
    const float* cqw  = (const float*)d_in[10];
    const float* cqb  = (const float*)d_in[11];
    const float* ckw  = (const float*)d_in[12];
    const float* ckb  = (const float*)d_in[13];
    const float* cvw  = (const float*)d_in[14];
    const float* cvb  = (const float*)d_in[15];
    const float* A_log= (const float*)d_in[16];
    const float* Dp   = (const float*)d_in[17];
    const float* dtb  = (const float*)d_in[18];
    const float* onw  = (const float*)d_in[19];
    float* out = (float*)d_out;

    char* p = (char*)d_ws;
    auto alloc = [&](size_t bytes) -> char* {
        char* r = p; p += (bytes + 255) & ~(size_t)255; return r;
    };
    const size_t NBT = (size_t)BT * Csz;          // 4M elements
    u16*   xbf   = (u16*)  alloc(NBT * 2);
    u16*   Wqbf  = (u16*)  alloc((size_t)Csz * Csz * 2);
    u16*   Wkbf  = (u16*)  alloc((size_t)Csz * Csz * 2);
    u16*   Wvbf  = (u16*)  alloc((size_t)Csz * Csz * 2);
    u16*   Wgbf  = (u16*)  alloc((size_t)Csz * Csz * 2);
    u16*   Wobf  = (u16*)  alloc((size_t)Csz * Csz * 2);
    u16*   qpre  = (u16*)  alloc(NBT * 2);
    u16*   kpre  = (u16*)  alloc(NBT * 2);        // contiguous with qpre
    u16*   vpre  = (u16*)  alloc(NBT * 2);
    u16*   gbf   = (u16*)  alloc(NBT * 2);
    float* qconv = (float*)alloc(NBT * 4);
    float* kconv = (float*)alloc(NBT * 4);
    float* ctab  = (float*)alloc((size_t)Tsz * 16 * 4);
    float* stab  = (float*)alloc((size_t)Tsz * 16 * 4);
    float* alpha = (float*)alloc((size_t)BT * Hsz * 4);
    float* beta  = (float*)alloc((size_t)BT * Hsz * 4);
    // overlays (stream-ordered reuse of dead buffers):
    float* vconv = (float*)qpre;   // 16MB over qpre+kpre (dead after conv_q/conv_k)
    u16*   oact  = (u16*)vpre;     // 8MB over vpre (dead after conv_v)

    // 1. rope tables
    rope_tables_k<<<(Tsz * 16 + 255) / 256, 256, 0, stream>>>(ctab, stab);

    // 2. f32 -> bf16 conversions
    cvt_f32_bf16_k<<<(int)(NBT / 4 + 255) / 256, 256, 0, stream>>>(x,  xbf,  (int)NBT);
    cvt_f32_bf16_k<<<(Csz * Csz / 4 + 255) / 256, 256, 0, stream>>>(Wq, Wqbf, Csz * Csz);
    cvt_f32_bf16_k<<<(Csz * Csz / 4 + 255) / 256, 256, 0, stream>>>(Wk, Wkbf, Csz * Csz);
    cvt_f32_bf16_k<<<(Csz * Csz / 4 + 255) / 256, 256, 0, stream>>>(Wv, Wvbf, Csz * Csz);
    cvt_f32_bf16_k<<<(Csz * Csz / 4 + 255) / 256, 256, 0, stream>>>(Wg, Wgbf, Csz * Csz);
    cvt_f32_bf16_k<<<(Csz * Csz / 4 + 255) / 256, 256, 0, stream>>>(Wo, Wobf, Csz * Csz);

    // 3. projections (bf16 out)
    dim3 ggrid(BT / 128, Csz / 128);
    gemm_bf16_nt<<<ggrid, 256, 0, stream>>>(xbf, Wqbf, nullptr, qpre, BT, Csz, Csz);
    gemm_bf16_nt<<<ggrid, 256, 0, stream>>>(xbf, Wkbf, nullptr, kpre, BT, Csz, Csz);
    gemm_bf16_nt<<<ggrid, 256, 0, stream>>>(xbf, Wvbf, nullptr, vpre, BT, Csz, Csz);
    gemm_bf16_nt<<<ggrid, 256, 0, stream>>>(xbf, Wgbf, nullptr, gbf,  BT, Csz, Csz);

    // 4. depthwise conv + silu (f32 out)
    dim3 cgrid(Bsz * (Tsz / 64), Csz / 256);
    conv_silu_k<<<cgrid, 256, 0, stream>>>(qpre, cqw, cqb, qconv);
    conv_silu_k<<<cgrid, 256, 0, stream>>>(kpre, ckw, ckb, kconv);
    conv_silu_k<<<cgrid, 256, 0, stream>>>(vpre, cvw, cvb, vconv);

    // 5. rope + l2norm, in place on q/k
    rope_l2norm_k<<<(Bsz * Tsz * Hsz) / 4, 256, 0, stream>>>(qconv, ctab, stab);
    rope_l2norm_k<<<(Bsz * Tsz * Hsz) / 4, 256, 0, stream>>>(kconv, ctab, stab);

    // 6. beta / alpha
    ab_k<<<BT, 256, 0, stream>>>(x, Wb, bb, Wgk, bgk, A_log, dtb, alpha, beta);

    // 7. recurrence (pure delta rule + D-skip, bf16 o out)
    recur_k<<<Bsz * Hsz, 64, 0, stream>>>(qconv, kconv, vconv, alpha, beta, Dp, oact);

    // 8. epilogue: rmsnorm + silu + gate, in place on oact
    epi_k<<<(BT * Hsz) / 4, 256, 0, stream>>>(oact, gbf, onw);

    // 9. output projection (f32 -> d_out)
    gemm_bf16_nt<<<ggrid, 256, 0, stream>>>(oact, Wobf, out, nullptr, BT, Csz, Csz);

    (void)in_sizes; (void)n_in; (void)out_size; (void)ws_size;
}

// Round 4
// 582.547 us; speedup vs baseline: 11.2620x; 3.5888x over previous
//
#include <hip/hip_runtime.h>

#define Bsz 2
#define Tsz 2048
#define Csz 1024
#define Hsz 16
#define Dsz 64
#define BT (Bsz*Tsz)   // 4096

typedef unsigned short u16;
typedef __attribute__((ext_vector_type(8))) short bf16x8_t;
typedef __attribute__((ext_vector_type(4))) float f32x4;
typedef __attribute__((ext_vector_type(4))) unsigned short us4;

#define MF(a,b,c) __builtin_amdgcn_mfma_f32_16x16x32_bf16(a,b,c,0,0,0)

__device__ __forceinline__ float bf2f(u16 u){
    union { unsigned i; float f; } c; c.i = ((unsigned)u) << 16; return c.f;
}
__device__ __forceinline__ u16 f2bf(float f){
    union { float f; unsigned i; } c; c.f = f;
    unsigned i = c.i;
    unsigned r = (i + 0x7fffu + ((i >> 16) & 1u)) >> 16;
    return (u16)r;
}

// ---------------------------------------------------------------- rope tables
__global__ void rope_tables_k(float* __restrict__ ctab, float* __restrict__ stab){
    int idx = blockIdx.x * blockDim.x + threadIdx.x;
    if (idx >= Tsz * 16) return;
    int t = idx >> 4, m = idx & 15;
    float arf = (float)m / 16.f;                   // ar[i]=i/32, i=2m
    double sb = 10000.0 * pow(32.0, 64.0 / 62.0);  // scaled_base
    float invf = (float)(1.0 / pow(sb, (double)arf));
    float fe   = (float)(1.0 / pow(10000.0, (double)arf));
    float wl   = 6.283185307179586f / fe;
    float ms   = fminf(fmaxf((wl - 1.0f) / 31.0f, 0.f), 1.f);
    float scale = 1.f + 31.f * ms;
    float freq = ((float)t / scale) * invf;
    ctab[idx] = cosf(freq);
    stab[idx] = sinf(freq);
}

// ---------------------------------------------------------------- f32 -> bf16
__global__ void cvt_f32_bf16_k(const float* __restrict__ in, u16* __restrict__ out, int n){
    int i = (blockIdx.x * blockDim.x + threadIdx.x) * 4;
    if (i >= n) return;
    float4 v = *(const float4*)(in + i);
    us4 o; o.x = f2bf(v.x); o.y = f2bf(v.y); o.z = f2bf(v.z); o.w = f2bf(v.w);
    *(us4*)(out + i) = o;
}

// ---------------------------------------------------------------- bf16 MFMA GEMM
__global__ __launch_bounds__(256) void gemm_bf16_nt(
    const u16* __restrict__ A, const u16* __restrict__ Bw,
    float* __restrict__ Cf, u16* __restrict__ Cb,
    int M, int N, int Kdim)
{
    const int l  = threadIdx.x & 63;
    const int w  = threadIdx.x >> 6;
    const int wm = (w >> 1) << 6;
    const int wn = (w & 1) << 6;
    const int lm = l & 15;
    const int lg = l >> 4;
    const long arow = (long)blockIdx.x * 128 + wm + lm;
    const long brow = (long)blockIdx.y * 128 + wn + lm;
    const u16* Ap = A + arow * Kdim + lg * 8;
    const u16* Bp = Bw + brow * Kdim + lg * 8;

    f32x4 acc[4][4];
#pragma unroll
    for (int i = 0; i < 4; i++)
#pragma unroll
        for (int j = 0; j < 4; j++) acc[i][j] = (f32x4){0.f, 0.f, 0.f, 0.f};

    for (int k0 = 0; k0 < Kdim; k0 += 32) {
        bf16x8_t av[4], bv[4];
#pragma unroll
        for (int i = 0; i < 4; i++) av[i] = *(const bf16x8_t*)(Ap + (long)i * 16 * Kdim + k0);
#pragma unroll
        for (int j = 0; j < 4; j++) bv[j] = *(const bf16x8_t*)(Bp + (long)j * 16 * Kdim + k0);
#pragma unroll
        for (int i = 0; i < 4; i++)
#pragma unroll
            for (int j = 0; j < 4; j++)
                acc[i][j] = MF(av[i], bv[j], acc[i][j]);
    }

    const int crow0 = blockIdx.x * 128 + wm + lg * 4;
    const int ccol0 = blockIdx.y * 128 + wn + lm;
#pragma unroll
    for (int i = 0; i < 4; i++)
#pragma unroll
        for (int j = 0; j < 4; j++)
#pragma unroll
            for (int r = 0; r < 4; r++) {
                long row = crow0 + i * 16 + r;
                long col = ccol0 + j * 16;
                float vv = acc[i][j][r];
                if (Cf) Cf[row * N + col] = vv;
                else    Cb[row * N + col] = f2bf(vv);
            }
}

// ---------------------------------------------------------------- depthwise conv K=4 + silu
__global__ __launch_bounds__(256) void conv_silu_k(
    const u16* __restrict__ pre, const float* __restrict__ w,
    const float* __restrict__ bias, float* __restrict__ out)
{
    int c  = blockIdx.y * 256 + threadIdx.x;
    int bi = blockIdx.x;              // B * (T/64)
    int b  = bi >> 5;
    int t0 = (bi & 31) << 6;
    float w0 = w[c*4+0], w1 = w[c*4+1], w2 = w[c*4+2], w3 = w[c*4+3];
    float bs = bias[c];
    long base = ((long)b * Tsz) * Csz + c;
    float xm3 = (t0 >= 3) ? bf2f(pre[base + (long)(t0-3)*Csz]) : 0.f;
    float xm2 = (t0 >= 2) ? bf2f(pre[base + (long)(t0-2)*Csz]) : 0.f;
    float xm1 = (t0 >= 1) ? bf2f(pre[base + (long)(t0-1)*Csz]) : 0.f;
    for (int t = t0; t < t0 + 64; t++) {
        float xc = bf2f(pre[base + (long)t * Csz]);
        float z  = bs + w0*xm3 + w1*xm2 + w2*xm1 + w3*xc;
        out[base + (long)t * Csz] = z / (1.f + expf(-z));
        xm3 = xm2; xm2 = xm1; xm1 = xc;
    }
}

// ---------------------------------------------------------------- rope + l2norm (in-place, f32)
__global__ __launch_bounds__(256) void rope_l2norm_k(
    float* __restrict__ qk, const float* __restrict__ ctab, const float* __restrict__ stab)
{
    int row = blockIdx.x * 4 + (threadIdx.x >> 6);
    int j   = threadIdx.x & 63;
    int t   = (row >> 4) & (Tsz - 1);
    int p   = j & 31, m = j & 15, hi = j >> 5;
    float2 xv = *(const float2*)(qk + (long)row * 64 + p * 2);
    float c = ctab[t * 16 + m], s = stab[t * 16 + m];
    float val = hi ? (xv.x * s + xv.y * c) : (xv.x * c - xv.y * s);
    float ss = val * val;
#pragma unroll
    for (int off = 1; off < 64; off <<= 1) ss += __shfl_xor(ss, off);
    float inv = 1.f / fmaxf(sqrtf(ss), 1e-12f);
    qk[(long)row * 64 + j] = val * inv;
}

// ---------------------------------------------------------------- beta / log-alpha
__global__ __launch_bounds__(256) void ab_k(
    const float* __restrict__ x,
    const float* __restrict__ Wb,  const float* __restrict__ bb,
    const float* __restrict__ Wgk, const float* __restrict__ bgk,
    const float* __restrict__ A_log, const float* __restrict__ dtb,
    float* __restrict__ lalpha, float* __restrict__ beta)
{
    __shared__ float xr[1024];
    int bt = blockIdx.x;
    const float* xp = x + (long)bt * 1024;
#pragma unroll
    for (int i = 0; i < 4; i++) xr[threadIdx.x + i * 256] = xp[threadIdx.x + i * 256];
    __syncthreads();
    int wv = threadIdx.x >> 6, l = threadIdx.x & 63;
#pragma unroll
    for (int oo = 0; oo < 8; oo++) {
        int o = wv * 8 + oo;           // 0..15: beta, 16..31: lalpha
        int h = o & 15;
        const float* wr = (o < 16 ? Wb : Wgk) + (long)h * 1024;
        float p = 0.f;
#pragma unroll
        for (int i = 0; i < 16; i++) p += wr[l + i * 64] * xr[l + i * 64];
        for (int off = 32; off; off >>= 1) p += __shfl_xor(p, off);
        if (l == 0) {
            if (o < 16) {
                beta[bt * 16 + h] = 1.f / (1.f + expf(-(p + bb[h])));
            } else {
                float gk = p + bgk[h] + dtb[h];
                float sp = gk > 0.f ? gk + log1pf(expf(-gk)) : log1pf(expf(gk));
                lalpha[bt * 16 + h] = -expf(A_log[h]) * sp;   // log(alpha)
            }
        }
    }
}

// ---------------------------------------------------------------- Phase A: per-chunk WY precompute
// tile = (b*16+h)*32 + n ; chunk length 64. Outputs (per tile, 64x64):
//  Wg (bf16)  : (I+L)^-1 diag(b*gamma) K      row t, col dk
//  U  (f32)   : (I+L)^-1 diag(b) V            row t, col dv
//  Amat (bf16): (gam_t/gam_s)(q_t.k_s), s<=t  row t, col s
//  Qg (bf16)  : gam_t * q_t                   row t, col dk
//  KpT (bf16) : (gam_end/gam_s) k_s[dk]       row dk, col s
//  gend (f32) : gam_end
__global__ __launch_bounds__(256) void chunk_prep_k(
    const float* __restrict__ q, const float* __restrict__ k, const float* __restrict__ v,
    const float* __restrict__ lalpha, const float* __restrict__ beta,
    u16* __restrict__ Wg_, u16* __restrict__ Amat_, u16* __restrict__ Qg_,
    u16* __restrict__ KpT_, float* __restrict__ U_, float* __restrict__ gend_)
{
    __shared__ u16   Kb[64][72];
    __shared__ u16   Qb[64][72];
    __shared__ float Lm[64][68];
    __shared__ float WU[64][132];
    __shared__ float lgS[64];
    __shared__ float betaS[64];

    const int tile = blockIdx.x;
    const int bh = tile >> 5, n = tile & 31;
    const int b = bh >> 4, h = bh & 15;
    const int t0 = n << 6;
    const int tid = threadIdx.x;
    const int lane = tid & 63, wv = tid >> 6;
    const int lm = lane & 15, lg = lane >> 4;

    // log-gamma inclusive scan + beta staging (wave 0)
    if (wv == 0) {
        long rix = ((long)(b * Tsz + t0 + lane)) * Hsz + h;
        float lgv = lalpha[rix];
#pragma unroll
        for (int off = 1; off < 64; off <<= 1) {
            float u = __shfl_up(lgv, off);
            if (lane >= off) lgv += u;
        }
        lgS[lane] = lgv;
        betaS[lane] = beta[rix];
    }
    // load K,Q tiles -> bf16 LDS
    {
        int row = tid >> 2, c0 = (tid & 3) << 4;
        long gb = ((long)(b * Tsz + t0 + row) * Hsz + h) << 6;
#pragma unroll
        for (int j = 0; j < 4; j++) {
            float4 kk = *(const float4*)(k + gb + c0 + 4*j);
            float4 qq = *(const float4*)(q + gb + c0 + 4*j);
            us4 kw, qw;
            kw.x=f2bf(kk.x); kw.y=f2bf(kk.y); kw.z=f2bf(kk.z); kw.w=f2bf(kk.w);
            qw.x=f2bf(qq.x); qw.y=f2bf(qq.y); qw.z=f2bf(qq.z); qw.w=f2bf(qq.w);
            *(us4*)&Kb[row][c0 + 4*j] = kw;
            *(us4*)&Qb[row][c0 + 4*j] = qw;
        }
    }
    __syncthreads();

    // Mkk, Mqk via MFMA; scaled L (f32 LDS) and Amat (bf16 global)
    {
        const int ar = 16*wv + lm;
        bf16x8_t Ka0 = *(const bf16x8_t*)&Kb[ar][8*lg];
        bf16x8_t Ka1 = *(const bf16x8_t*)&Kb[ar][32 + 8*lg];
        bf16x8_t Qa0 = *(const bf16x8_t*)&Qb[ar][8*lg];
        bf16x8_t Qa1 = *(const bf16x8_t*)&Qb[ar][32 + 8*lg];
        f32x4 aKK[4], aQK[4];
#pragma unroll
        for (int nt=0; nt<4; nt++){ aKK[nt]=(f32x4){0,0,0,0}; aQK[nt]=(f32x4){0,0,0,0}; }
#pragma unroll
        for (int nt=0; nt<4; nt++){
            int br = 16*nt + lm;
            bf16x8_t B0 = *(const bf16x8_t*)&Kb[br][8*lg];
            bf16x8_t B1 = *(const bf16x8_t*)&Kb[br][32 + 8*lg];
            aKK[nt] = MF(Ka0, B0, aKK[nt]); aKK[nt] = MF(Ka1, B1, aKK[nt]);
            aQK[nt] = MF(Qa0, B0, aQK[nt]); aQK[nt] = MF(Qa1, B1, aQK[nt]);
        }
#pragma unroll
        for (int r=0; r<4; r++){
            int t = 16*wv + 4*lg + r;
            float lgt = lgS[t];
            float bt = betaS[t];
#pragma unroll
            for (int nt=0; nt<4; nt++){
                int s = 16*nt + lm;
                float ratio = expf(lgt - lgS[s]);
                Lm[t][s] = (s < t) ? bt * ratio * aKK[nt][r] : 0.f;
                Amat_[(long)tile*4096 + t*64 + s] = f2bf((s <= t) ? ratio * aQK[nt][r] : 0.f);
            }
        }
    }
    // init WU = [diag(b*gamma)K | diag(b)V]  (f32, from global)
    {
        int row = tid >> 2, qd = tid & 3;
        long gb = ((long)(b * Tsz + t0 + row) * Hsz + h) << 6;
        float bt = betaS[row];
        float gt = expf(lgS[row]);
        if (qd < 2) {
            int c0 = qd * 32;
            float bg = bt * gt;
#pragma unroll
            for (int j = 0; j < 8; j++) {
                float4 kk = *(const float4*)(k + gb + c0 + 4*j);
                WU[row][c0+4*j+0] = bg*kk.x; WU[row][c0+4*j+1] = bg*kk.y;
                WU[row][c0+4*j+2] = bg*kk.z; WU[row][c0+4*j+3] = bg*kk.w;
            }
        } else {
            int c0 = (qd - 2) * 32;
#pragma unroll
            for (int j = 0; j < 8; j++) {
                float4 vv = *(const float4*)(v + gb + c0 + 4*j);
                WU[row][64+c0+4*j+0] = bt*vv.x; WU[row][64+c0+4*j+1] = bt*vv.y;
                WU[row][64+c0+4*j+2] = bt*vv.z; WU[row][64+c0+4*j+3] = bt*vv.w;
            }
        }
    }
    __syncthreads();

    // forward substitution: (I+L) WU = rhs
    for (int t = 1; t < 64; t++) {
        if (tid < 128) {
            float acc = WU[t][tid];
            const float* Lr = Lm[t];
            int s = 0;
            for (; s + 1 < t; s += 2)
                acc -= Lr[s]*WU[s][tid] + Lr[s+1]*WU[s+1][tid];
            if (s < t) acc -= Lr[s]*WU[s][tid];
            WU[t][tid] = acc;
        }
        __syncthreads();
    }

    // outputs
    {
        int row = tid >> 2, c0 = (tid & 3) << 4;
        float gt  = expf(lgS[row]);
        float lge = lgS[63];
        long tb = (long)tile * 4096;
#pragma unroll
        for (int c = c0; c < c0 + 16; c++) {
            Wg_[tb + row*64 + c] = f2bf(WU[row][c]);
            U_ [tb + row*64 + c] = WU[row][64 + c];
            Qg_[tb + row*64 + c] = f2bf(gt * bf2f(Qb[row][c]));
            KpT_[tb + row*64 + c] = f2bf(expf(lge - lgS[c]) * bf2f(Kb[c][row]));
        }
        if (tid == 0) gend_[tile] = expf(lge);
    }
}

// ---------------------------------------------------------------- Phase B: sequential chunk scan
// 32 blocks (one per (b,h)), 4 waves. S kept f32 in LDS; consumed hi/lo bf16.
__global__ __launch_bounds__(256) void chunk_scan_k(
    const u16* __restrict__ Wg_, const u16* __restrict__ Amat_, const u16* __restrict__ Qg_,
    const u16* __restrict__ KpT_, const float* __restrict__ U_, const float* __restrict__ gend_,
    u16* __restrict__ oact)
{
    __shared__ float Sl[64][68];
    __shared__ u16   CT[64][72];
    const int bh = blockIdx.x, b = bh >> 4, h = bh & 15;
    const int tid = threadIdx.x, lane = tid & 63, wv = tid >> 6;
    const int lm = lane & 15, lg = lane >> 4;

    for (int i = tid; i < 64*68; i += 256) (&Sl[0][0])[i] = 0.f;
    __syncthreads();

    for (int n = 0; n < 32; n++) {
        const long tb = ((long)(bh*32 + n)) << 12;
        const int ar = 16*wv + lm;
        // global per-chunk operands
        bf16x8_t Wa0 = *(const bf16x8_t*)(Wg_  + tb + ar*64 + 8*lg);
        bf16x8_t Wa1 = *(const bf16x8_t*)(Wg_  + tb + ar*64 + 32 + 8*lg);
        bf16x8_t Qa0 = *(const bf16x8_t*)(Qg_  + tb + ar*64 + 8*lg);
        bf16x8_t Qa1 = *(const bf16x8_t*)(Qg_  + tb + ar*64 + 32 + 8*lg);
        bf16x8_t Aa0 = *(const bf16x8_t*)(Amat_+ tb + ar*64 + 8*lg);
        bf16x8_t Aa1 = *(const bf16x8_t*)(Amat_+ tb + ar*64 + 32 + 8*lg);
        bf16x8_t Kp[4][2];
#pragma unroll
        for (int nt=0; nt<4; nt++)
#pragma unroll
            for (int sh=0; sh<2; sh++)
                Kp[nt][sh] = *(const bf16x8_t*)(KpT_ + tb + (16*nt+lm)*64 + 32*sh + 8*lg);
        float Uv[4][4];
#pragma unroll
        for (int nt=0; nt<4; nt++)
#pragma unroll
            for (int r=0; r<4; r++)
                Uv[nt][r] = U_[tb + (16*wv + 4*lg + r)*64 + 16*nt + lm];
        const float ge = gend_[bh*32 + n];

        // S fragments (B-layout, hi/lo split) + S acc-layout copy
        bf16x8_t Shi[4][2], Slo[4][2];
#pragma unroll
        for (int nt=0; nt<4; nt++)
#pragma unroll
            for (int kh=0; kh<2; kh++){
                const float* sp = &Sl[16*nt + lm][32*kh + 8*lg];
                float4 aa = *(const float4*)sp;
                float4 bb = *(const float4*)(sp + 4);
                float xs[8] = {aa.x,aa.y,aa.z,aa.w,bb.x,bb.y,bb.z,bb.w};
#pragma unroll
                for (int j=0; j<8; j++){
                    u16 hv = f2bf(xs[j]);
                    Shi[nt][kh][j] = (short)hv;
                    Slo[nt][kh][j] = (short)f2bf(xs[j] - bf2f(hv));
                }
            }
        float Sa[4][4];
#pragma unroll
        for (int nt=0; nt<4; nt++)
#pragma unroll
            for (int r=0; r<4; r++)
                Sa[nt][r] = Sl[16*wv + 4*lg + r][16*nt + lm];

        // P = W * S^T (hi+lo)
        f32x4 accP[4];
#pragma unroll
        for (int nt=0; nt<4; nt++){
            accP[nt] = (f32x4){0,0,0,0};
            accP[nt] = MF(Wa0, Shi[nt][0], accP[nt]);
            accP[nt] = MF(Wa0, Slo[nt][0], accP[nt]);
            accP[nt] = MF(Wa1, Shi[nt][1], accP[nt]);
            accP[nt] = MF(Wa1, Slo[nt][1], accP[nt]);
        }
        // C = U - P -> CT (bf16, transposed)
#pragma unroll
        for (int nt=0; nt<4; nt++)
#pragma unroll
            for (int r=0; r<4; r++)
                CT[16*nt + lm][16*wv + 4*lg + r] = f2bf(Uv[nt][r] - accP[nt][r]);
        // O1 = gam*Q * S^T (hi+lo)
        f32x4 accO[4];
#pragma unroll
        for (int nt=0; nt<4; nt++){
            accO[nt] = (f32x4){0,0,0,0};
            accO[nt] = MF(Qa0, Shi[nt][0], accO[nt]);
            accO[nt] = MF(Qa0, Slo[nt][0], accO[nt]);
            accO[nt] = MF(Qa1, Shi[nt][1], accO[nt]);
            accO[nt] = MF(Qa1, Slo[nt][1], accO[nt]);
        }
        __syncthreads();   // CT complete; S reads complete

        // O2 = Amat * C^T
#pragma unroll
        for (int nt=0; nt<4; nt++){
            bf16x8_t C0 = *(const bf16x8_t*)&CT[16*nt + lm][8*lg];
            bf16x8_t C1 = *(const bf16x8_t*)&CT[16*nt + lm][32 + 8*lg];
            accO[nt] = MF(Aa0, C0, accO[nt]);
            accO[nt] = MF(Aa1, C1, accO[nt]);
        }
        // S' = gend*S + Kp'^T C
        bf16x8_t CTa0 = *(const bf16x8_t*)&CT[16*wv + lm][8*lg];
        bf16x8_t CTa1 = *(const bf16x8_t*)&CT[16*wv + lm][32 + 8*lg];
        f32x4 accS[4];
#pragma unroll
        for (int nt=0; nt<4; nt++){
            accS[nt] = (f32x4){ge*Sa[nt][0], ge*Sa[nt][1], ge*Sa[nt][2], ge*Sa[nt][3]};
            accS[nt] = MF(CTa0, Kp[nt][0], accS[nt]);
            accS[nt] = MF(CTa1, Kp[nt][1], accS[nt]);
        }
        // write back S and o
#pragma unroll
        for (int nt=0; nt<4; nt++)
#pragma unroll
            for (int r=0; r<4; r++)
                Sl[16*wv + 4*lg + r][16*nt + lm] = accS[nt][r];
        const int trow = n*64 + 16*wv + 4*lg;
#pragma unroll
        for (int nt=0; nt<4; nt++)
#pragma unroll
            for (int r=0; r<4; r++)
                oact[(long)(b*Tsz + trow + r)*1024 + h*64 + 16*nt + lm] = f2bf(accO[nt][r]);
        __syncthreads();   // S write / CT reads complete before next chunk
    }
}

// ---------------------------------------------------------------- epilogue: +Dp*v, rmsnorm, silu, gate
__global__ __launch_bounds__(256) void epi2_k(
    u16* __restrict__ o, const u16* __restrict__ g, const float* __restrict__ vc,
    const float* __restrict__ Dp, const float* __restrict__ onw)
{
    long row = (long)blockIdx.x * 4 + (threadIdx.x >> 6);
    int lane = threadIdx.x & 63;
    int h = (int)(row & 15);
    long idx = (row << 6) + lane;
    float ov = bf2f(o[idx]) + Dp[h] * vc[idx];
    float gv = bf2f(g[idx]);
    float ss = ov * ov;
#pragma unroll
    for (int off = 1; off < 64; off <<= 1) ss += __shfl_xor(ss, off);
    float r   = rsqrtf(ss * (1.f / 64.f) + 1e-6f);
    float on  = onw[lane] * (ov * r);
    float sil = on / (1.f + expf(-on));
    o[idx] = f2bf(gv * sil);
}

// ---------------------------------------------------------------- host launch
extern "C" void kernel_launch(void* const* d_in, const int* in_sizes, int n_in,
                              void* d_out, int out_size, void* d_ws, size_t ws_size,
                              hipStream_t stream)
{
    const float* x    = (const float*)d_in[0];
    const float* Wq   = (const float*)d_in[1];
    const float* Wk   = (const float*)d_in[2];
    const float* Wv   = (const float*)d_in[3];
    const float* Wg   = (const float*)d_in[4];
    const float* Wo   = (const float*)d_in[5];
    const float* Wb   = (const float*)d_in[6];
    const float* bb   = (const float*)d_in[7];
    const float* Wgk  = (const float*)d_in[8];
    const float* bgk  = (const float*)d_in[9];
    const float* cqw  = (const float*)d_in[10];
    const float* cqb  = (const float*)d_in[11];
    const float* ckw  = (const float*)d_in[12];
    const float* ckb  = (const float*)d_in[13];
    const float* cvw  = (const float*)d_in[14];
    const float* cvb  = (const float*)d_in[15];
    const float* A_log= (const float*)d_in[16];
    const float* Dp   = (const float*)d_in[17];
    const float* dtb  = (const float*)d_in[18];
    const float* onw  = (const float*)d_in[19];
    float* out = (float*)d_out;

    char* p = (char*)d_ws;
    auto alloc = [&](size_t bytes) -> char* {
        char* r = p; p += (bytes + 255) & ~(size_t)255; return r;
    };
    const size_t NBT = (size_t)BT * Csz;          // 4M elements
    const size_t NTILE = (size_t)32 * 32;         // 1024 chunk tiles
    u16*   xbf   = (u16*)  alloc(NBT * 2);
    u16*   Wqbf  = (u16*)  alloc((size_t)Csz * Csz * 2);
    u16*   Wkbf  = (u16*)  alloc((size_t)Csz * Csz * 2);
    u16*   Wvbf  = (u16*)  alloc((size_t)Csz * Csz * 2);
    u16*   Wgbf  = (u16*)  alloc((size_t)Csz * Csz * 2);
    u16*   Wobf  = (u16*)  alloc((size_t)Csz * Csz * 2);
    u16*   qpre  = (u16*)  alloc(NBT * 2);
    u16*   kpre  = (u16*)  alloc(NBT * 2);        // contiguous with qpre
    u16*   vpre  = (u16*)  alloc(NBT * 2);
    u16*   gbf   = (u16*)  alloc(NBT * 2);
    float* qconv = (float*)alloc(NBT * 4);
    float* kconv = (float*)alloc(NBT * 4);
    float* ctab  = (float*)alloc((size_t)Tsz * 16 * 4);
    float* stab  = (float*)alloc((size_t)Tsz * 16 * 4);
    float* lalpha= (float*)alloc((size_t)BT * Hsz * 4);
    float* beta  = (float*)alloc((size_t)BT * Hsz * 4);
    u16*   Wg_t  = (u16*)  alloc(NTILE * 4096 * 2);
    u16*   Amat_t= (u16*)  alloc(NTILE * 4096 * 2);
    u16*   Qg_t  = (u16*)  alloc(NTILE * 4096 * 2);
    u16*   KpT_t = (u16*)  alloc(NTILE * 4096 * 2);
    float* U_t   = (float*)alloc(NTILE * 4096 * 4);
    float* gend_t= (float*)alloc(NTILE * 4);
    // overlays (stream-ordered reuse of dead buffers):
    float* vconv = (float*)qpre;   // 16MB over qpre+kpre (dead after conv_q/conv_k)
    u16*   oact  = (u16*)vpre;     // 8MB over vpre (dead after conv_v)

    // 1. rope tables
    rope_tables_k<<<(Tsz * 16 + 255) / 256, 256, 0, stream>>>(ctab, stab);

    // 2. f32 -> bf16 conversions
    cvt_f32_bf16_k<<<(int)(NBT / 4 + 255) / 256, 256, 0, stream>>>(x,  xbf,  (int)NBT);
    cvt_f32_bf16_k<<<(Csz * Csz / 4 + 255) / 256, 256, 0, stream>>>(Wq, Wqbf, Csz * Csz);
    cvt_f32_bf16_k<<<(Csz * Csz / 4 + 255) / 256, 256, 0, stream>>>(Wk, Wkbf, Csz * Csz);
    cvt_f32_bf16_k<<<(Csz * Csz / 4 + 255) / 256, 256, 0, stream>>>(Wv, Wvbf, Csz * Csz);
    cvt_f32_bf16_k<<<(Csz * Csz / 4 + 255) / 256, 256, 0, stream>>>(Wg, Wgbf, Csz * Csz);
    cvt_f32_bf16_k<<<(Csz * Csz / 4 + 255) / 256, 256, 0, stream>>>(Wo, Wobf, Csz * Csz);

    // 3. projections (bf16 out)
    dim3 ggrid(BT / 128, Csz / 128);
    gemm_bf16_nt<<<ggrid, 256, 0, stream>>>(xbf, Wqbf, nullptr, qpre, BT, Csz, Csz);
    gemm_bf16_nt<<<ggrid, 256, 0, stream>>>(xbf, Wkbf, nullptr, kpre, BT, Csz, Csz);
    gemm_bf16_nt<<<ggrid, 256, 0, stream>>>(xbf, Wvbf, nullptr, vpre, BT, Csz, Csz);
    gemm_bf16_nt<<<ggrid, 256, 0, stream>>>(xbf, Wgbf, nullptr, gbf,  BT, Csz, Csz);

    // 4. depthwise conv + silu (f32 out)
    dim3 cgrid(Bsz * (Tsz / 64), Csz / 256);
    conv_silu_k<<<cgrid, 256, 0, stream>>>(qpre, cqw, cqb, qconv);
    conv_silu_k<<<cgrid, 256, 0, stream>>>(kpre, ckw, ckb, kconv);
    conv_silu_k<<<cgrid, 256, 0, stream>>>(vpre, cvw, cvb, vconv);

    // 5. rope + l2norm, in place on q/k
    rope_l2norm_k<<<(Bsz * Tsz * Hsz) / 4, 256, 0, stream>>>(qconv, ctab, stab);
    rope_l2norm_k<<<(Bsz * Tsz * Hsz) / 4, 256, 0, stream>>>(kconv, ctab, stab);

    // 6. beta / log-alpha
    ab_k<<<BT, 256, 0, stream>>>(x, Wb, bb, Wgk, bgk, A_log, dtb, lalpha, beta);

    // 7a. chunk precompute (parallel over 1024 tiles)
    chunk_prep_k<<<1024, 256, 0, stream>>>(qconv, kconv, vconv, lalpha, beta,
                                           Wg_t, Amat_t, Qg_t, KpT_t, U_t, gend_t);

    // 7b. sequential chunk scan (32 blocks)
    chunk_scan_k<<<Bsz * Hsz, 256, 0, stream>>>(Wg_t, Amat_t, Qg_t, KpT_t, U_t, gend_t, oact);

    // 8. epilogue: D-skip + rmsnorm + silu + gate, in place on oact
    epi2_k<<<(BT * Hsz) / 4, 256, 0, stream>>>(oact, gbf, vconv, Dp, onw);

    // 9. output projection (f32 -> d_out)
    gemm_bf16_nt<<<ggrid, 256, 0, stream>>>(oact, Wobf, out, nullptr, BT, Csz, Csz);

    (void)in_sizes; (void)n_in; (void)out_size; (void)ws_size;
}

// Round 6
// 545.123 us; speedup vs baseline: 12.0351x; 1.0687x over previous
//
#include <hip/hip_runtime.h>

#define Bsz 2
#define Tsz 2048
#define Csz 1024
#define Hsz 16
#define Dsz 64
#define BT (Bsz*Tsz)   // 4096

typedef unsigned short u16;
typedef __attribute__((ext_vector_type(8))) short bf16x8_t;
typedef __attribute__((ext_vector_type(4))) float f32x4;
typedef __attribute__((ext_vector_type(4))) unsigned short us4;

#define MF(a,b,c) __builtin_amdgcn_mfma_f32_16x16x32_bf16(a,b,c,0,0,0)

__device__ __forceinline__ float bf2f(u16 u){
    union { unsigned i; float f; } c; c.i = ((unsigned)u) << 16; return c.f;
}
__device__ __forceinline__ u16 f2bf(float f){
    union { float f; unsigned i; } c; c.f = f;
    unsigned i = c.i;
    unsigned r = (i + 0x7fffu + ((i >> 16) & 1u)) >> 16;
    return (u16)r;
}

// ---------------------------------------------------------------- rope tables
__global__ void rope_tables_k(float* __restrict__ ctab, float* __restrict__ stab){
    int idx = blockIdx.x * blockDim.x + threadIdx.x;
    if (idx >= Tsz * 16) return;
    int t = idx >> 4, m = idx & 15;
    float arf = (float)m / 16.f;                   // ar[i]=i/32, i=2m
    double sb = 10000.0 * pow(32.0, 64.0 / 62.0);  // scaled_base
    float invf = (float)(1.0 / pow(sb, (double)arf));
    float fe   = (float)(1.0 / pow(10000.0, (double)arf));
    float wl   = 6.283185307179586f / fe;
    float ms   = fminf(fmaxf((wl - 1.0f) / 31.0f, 0.f), 1.f);
    float scale = 1.f + 31.f * ms;
    float freq = ((float)t / scale) * invf;
    ctab[idx] = cosf(freq);
    stab[idx] = sinf(freq);
}

// ---------------------------------------------------------------- f32 -> bf16
__global__ void cvt_f32_bf16_k(const float* __restrict__ in, u16* __restrict__ out, int n){
    int i = (blockIdx.x * blockDim.x + threadIdx.x) * 4;
    if (i >= n) return;
    float4 v = *(const float4*)(in + i);
    us4 o; o.x = f2bf(v.x); o.y = f2bf(v.y); o.z = f2bf(v.z); o.w = f2bf(v.w);
    *(us4*)(out + i) = o;
}

// ---------------------------------------------------------------- bf16 MFMA GEMM
// 1D grid with bijective XCD swizzle (requires gridDim.x % 8 == 0).
// C[m][col]: if Cf != null -> f32 at Cf[m*1024+col] (N<=1024);
// else bf16 split-store: Cb[(col>>10)*sstride + m*1024 + (col&1023)].
__global__ __launch_bounds__(256) void gemm_bf16_nt(
    const u16* __restrict__ A, const u16* __restrict__ Bw,
    float* __restrict__ Cf, u16* __restrict__ Cb,
    int gm, long sstride, int Kdim)
{
    const int nwg = gridDim.x;
    const int q8  = nwg >> 3;
    const int id  = blockIdx.x;
    const int swz = (id & 7) * q8 + (id >> 3);
    const int bx  = swz % gm;
    const int by  = swz / gm;

    const int l  = threadIdx.x & 63;
    const int w  = threadIdx.x >> 6;
    const int wm = (w >> 1) << 6;
    const int wn = (w & 1) << 6;
    const int lm = l & 15;
    const int lg = l >> 4;
    const long arow = (long)bx * 128 + wm + lm;
    const long brow = (long)by * 128 + wn + lm;
    const u16* Ap = A + arow * Kdim + lg * 8;
    const u16* Bp = Bw + brow * Kdim + lg * 8;

    f32x4 acc[4][4];
#pragma unroll
    for (int i = 0; i < 4; i++)
#pragma unroll
        for (int j = 0; j < 4; j++) acc[i][j] = (f32x4){0.f, 0.f, 0.f, 0.f};

    for (int k0 = 0; k0 < Kdim; k0 += 32) {
        bf16x8_t av[4], bv[4];
#pragma unroll
        for (int i = 0; i < 4; i++) av[i] = *(const bf16x8_t*)(Ap + (long)i * 16 * Kdim + k0);
#pragma unroll
        for (int j = 0; j < 4; j++) bv[j] = *(const bf16x8_t*)(Bp + (long)j * 16 * Kdim + k0);
#pragma unroll
        for (int i = 0; i < 4; i++)
#pragma unroll
            for (int j = 0; j < 4; j++)
                acc[i][j] = MF(av[i], bv[j], acc[i][j]);
    }

    const int crow0 = bx * 128 + wm + lg * 4;
    const int ccol0 = by * 128 + wn + lm;
#pragma unroll
    for (int i = 0; i < 4; i++)
#pragma unroll
        for (int j = 0; j < 4; j++)
#pragma unroll
            for (int r = 0; r < 4; r++) {
                long row = crow0 + i * 16 + r;
                int  col = ccol0 + j * 16;
                float vv = acc[i][j][r];
                if (Cf) Cf[row * 1024 + col] = vv;
                else    Cb[(long)(col >> 10) * sstride + row * 1024 + (col & 1023)] = f2bf(vv);
            }
}

// ---------------------------------------------------------------- depthwise conv K=4 + silu
__global__ __launch_bounds__(256) void conv_silu_k(
    const u16* __restrict__ pre, const float* __restrict__ w,
    const float* __restrict__ bias, float* __restrict__ out)
{
    int c  = blockIdx.y * 256 + threadIdx.x;
    int bi = blockIdx.x;              // B * (T/64)
    int b  = bi >> 5;
    int t0 = (bi & 31) << 6;
    float w0 = w[c*4+0], w1 = w[c*4+1], w2 = w[c*4+2], w3 = w[c*4+3];
    float bs = bias[c];
    long base = ((long)b * Tsz) * Csz + c;
    float xm3 = (t0 >= 3) ? bf2f(pre[base + (long)(t0-3)*Csz]) : 0.f;
    float xm2 = (t0 >= 2) ? bf2f(pre[base + (long)(t0-2)*Csz]) : 0.f;
    float xm1 = (t0 >= 1) ? bf2f(pre[base + (long)(t0-1)*Csz]) : 0.f;
    for (int t = t0; t < t0 + 64; t++) {
        float xc = bf2f(pre[base + (long)t * Csz]);
        float z  = bs + w0*xm3 + w1*xm2 + w2*xm1 + w3*xc;
        out[base + (long)t * Csz] = z / (1.f + expf(-z));
        xm3 = xm2; xm2 = xm1; xm1 = xc;
    }
}

// ---------------------------------------------------------------- rope + l2norm (in-place, f32)
__global__ __launch_bounds__(256) void rope_l2norm_k(
    float* __restrict__ qk, const float* __restrict__ ctab, const float* __restrict__ stab)
{
    int row = blockIdx.x * 4 + (threadIdx.x >> 6);
    int j   = threadIdx.x & 63;
    int t   = (row >> 4) & (Tsz - 1);
    int p   = j & 31, m = j & 15, hi = j >> 5;
    float2 xv = *(const float2*)(qk + (long)row * 64 + p * 2);
    float c = ctab[t * 16 + m], s = stab[t * 16 + m];
    float val = hi ? (xv.x * s + xv.y * c) : (xv.x * c - xv.y * s);
    float ss = val * val;
#pragma unroll
    for (int off = 1; off < 64; off <<= 1) ss += __shfl_xor(ss, off);
    float inv = 1.f / fmaxf(sqrtf(ss), 1e-12f);
    qk[(long)row * 64 + j] = val * inv;
}

// ---------------------------------------------------------------- beta / log-alpha
__global__ __launch_bounds__(256) void ab_k(
    const float* __restrict__ x,
    const float* __restrict__ Wb,  const float* __restrict__ bb,
    const float* __restrict__ Wgk, const float* __restrict__ bgk,
    const float* __restrict__ A_log, const float* __restrict__ dtb,
    float* __restrict__ lalpha, float* __restrict__ beta)
{
    __shared__ float xr[1024];
    int bt = blockIdx.x;
    const float* xp = x + (long)bt * 1024;
#pragma unroll
    for (int i = 0; i < 4; i++) xr[threadIdx.x + i * 256] = xp[threadIdx.x + i * 256];
    __syncthreads();
    int wv = threadIdx.x >> 6, l = threadIdx.x & 63;
#pragma unroll
    for (int oo = 0; oo < 8; oo++) {
        int o = wv * 8 + oo;           // 0..15: beta, 16..31: lalpha
        int h = o & 15;
        const float* wr = (o < 16 ? Wb : Wgk) + (long)h * 1024;
        float p = 0.f;
#pragma unroll
        for (int i = 0; i < 16; i++) p += wr[l + i * 64] * xr[l + i * 64];
        for (int off = 32; off; off >>= 1) p += __shfl_xor(p, off);
        if (l == 0) {
            if (o < 16) {
                beta[bt * 16 + h] = 1.f / (1.f + expf(-(p + bb[h])));
            } else {
                float gk = p + bgk[h] + dtb[h];
                float sp = gk > 0.f ? gk + log1pf(expf(-gk)) : log1pf(expf(gk));
                lalpha[bt * 16 + h] = -expf(A_log[h]) * sp;   // log(alpha)
            }
        }
    }
}

// ---------------------------------------------------------------- Phase A: per-chunk WY precompute
__global__ __launch_bounds__(256) void chunk_prep_k(
    const float* __restrict__ q, const float* __restrict__ k, const float* __restrict__ v,
    const float* __restrict__ lalpha, const float* __restrict__ beta,
    u16* __restrict__ Wg_, u16* __restrict__ Amat_, u16* __restrict__ Qg_,
    u16* __restrict__ KpT_, float* __restrict__ U_, float* __restrict__ gend_)
{
    __shared__ u16   Kb[64][72];
    __shared__ u16   Qb[64][72];
    __shared__ float Lm[64][68];
    __shared__ float WU[64][132];
    __shared__ float lgS[64];
    __shared__ float betaS[64];

    const int tile = blockIdx.x;
    const int bh = tile >> 5, n = tile & 31;
    const int b = bh >> 4, h = bh & 15;
    const int t0 = n << 6;
    const int tid = threadIdx.x;
    const int lane = tid & 63, wv = tid >> 6;
    const int lm = lane & 15, lg = lane >> 4;

    // log-gamma inclusive scan + beta staging (wave 0)
    if (wv == 0) {
        long rix = ((long)(b * Tsz + t0 + lane)) * Hsz + h;
        float lgv = lalpha[rix];
#pragma unroll
        for (int off = 1; off < 64; off <<= 1) {
            float u = __shfl_up(lgv, off);
            if (lane >= off) lgv += u;
        }
        lgS[lane] = lgv;
        betaS[lane] = beta[rix];
    }
    // load K,Q tiles -> bf16 LDS
    {
        int row = tid >> 2, c0 = (tid & 3) << 4;
        long gb = ((long)(b * Tsz + t0 + row) * Hsz + h) << 6;
#pragma unroll
        for (int j = 0; j < 4; j++) {
            float4 kk = *(const float4*)(k + gb + c0 + 4*j);
            float4 qq = *(const float4*)(q + gb + c0 + 4*j);
            us4 kw, qw;
            kw.x=f2bf(kk.x); kw.y=f2bf(kk.y); kw.z=f2bf(kk.z); kw.w=f2bf(kk.w);
            qw.x=f2bf(qq.x); qw.y=f2bf(qq.y); qw.z=f2bf(qq.z); qw.w=f2bf(qq.w);
            *(us4*)&Kb[row][c0 + 4*j] = kw;
            *(us4*)&Qb[row][c0 + 4*j] = qw;
        }
    }
    __syncthreads();

    // Mkk, Mqk via MFMA; scaled L (f32 LDS) and Amat (bf16 global)
    {
        const int ar = 16*wv + lm;
        bf16x8_t Ka0 = *(const bf16x8_t*)&Kb[ar][8*lg];
        bf16x8_t Ka1 = *(const bf16x8_t*)&Kb[ar][32 + 8*lg];
        bf16x8_t Qa0 = *(const bf16x8_t*)&Qb[ar][8*lg];
        bf16x8_t Qa1 = *(const bf16x8_t*)&Qb[ar][32 + 8*lg];
        f32x4 aKK[4], aQK[4];
#pragma unroll
        for (int nt=0; nt<4; nt++){ aKK[nt]=(f32x4){0,0,0,0}; aQK[nt]=(f32x4){0,0,0,0}; }
#pragma unroll
        for (int nt=0; nt<4; nt++){
            int br = 16*nt + lm;
            bf16x8_t B0 = *(const bf16x8_t*)&Kb[br][8*lg];
            bf16x8_t B1 = *(const bf16x8_t*)&Kb[br][32 + 8*lg];
            aKK[nt] = MF(Ka0, B0, aKK[nt]); aKK[nt] = MF(Ka1, B1, aKK[nt]);
            aQK[nt] = MF(Qa0, B0, aQK[nt]); aQK[nt] = MF(Qa1, B1, aQK[nt]);
        }
#pragma unroll
        for (int r=0; r<4; r++){
            int t = 16*wv + 4*lg + r;
            float lgt = lgS[t];
            float bt = betaS[t];
#pragma unroll
            for (int nt=0; nt<4; nt++){
                int s = 16*nt + lm;
                float ratio = expf(lgt - lgS[s]);
                Lm[t][s] = (s < t) ? bt * ratio * aKK[nt][r] : 0.f;
                Amat_[(long)tile*4096 + t*64 + s] = f2bf((s <= t) ? ratio * aQK[nt][r] : 0.f);
            }
        }
    }
    // init WU = [diag(b*gamma)K | diag(b)V]  (f32, from global)
    {
        int row = tid >> 2, qd = tid & 3;
        long gb = ((long)(b * Tsz + t0 + row) * Hsz + h) << 6;
        float bt = betaS[row];
        float gt = expf(lgS[row]);
        if (qd < 2) {
            int c0 = qd * 32;
            float bg = bt * gt;
#pragma unroll
            for (int j = 0; j < 8; j++) {
                float4 kk = *(const float4*)(k + gb + c0 + 4*j);
                WU[row][c0+4*j+0] = bg*kk.x; WU[row][c0+4*j+1] = bg*kk.y;
                WU[row][c0+4*j+2] = bg*kk.z; WU[row][c0+4*j+3] = bg*kk.w;
            }
        } else {
            int c0 = (qd - 2) * 32;
#pragma unroll
            for (int j = 0; j < 8; j++) {
                float4 vv = *(const float4*)(v + gb + c0 + 4*j);
                WU[row][64+c0+4*j+0] = bt*vv.x; WU[row][64+c0+4*j+1] = bt*vv.y;
                WU[row][64+c0+4*j+2] = bt*vv.z; WU[row][64+c0+4*j+3] = bt*vv.w;
            }
        }
    }
    __syncthreads();

    // forward substitution: (I+L) X = rhs, column-owned, X in registers.
    // Thread tid < 128 owns column tid of [W|U]; zero cross-thread deps, zero barriers.
    if (tid < 128) {
        float X[64];
        X[0] = WU[0][tid];
#pragma unroll
        for (int r = 1; r < 64; r++) {
            float a0 = 0.f, a1 = 0.f, a2 = 0.f, a3 = 0.f;
            const float4* L4 = (const float4*)&Lm[r][0];
#pragma unroll
            for (int j = 0; 4*j < r; j++) {
                float4 lv = L4[j];                // wave-uniform broadcast read
                int s = 4*j;
                a0 += lv.x * X[s];
                if (s+1 < r) a1 += lv.y * X[s+1];
                if (s+2 < r) a2 += lv.z * X[s+2];
                if (s+3 < r) a3 += lv.w * X[s+3];
            }
            X[r] = WU[r][tid] - ((a0+a1)+(a2+a3));
        }
#pragma unroll
        for (int r = 0; r < 64; r++) WU[r][tid] = X[r];
    }
    __syncthreads();

    // outputs
    {
        int row = tid >> 2, c0 = (tid & 3) << 4;
        float gt  = expf(lgS[row]);
        float lge = lgS[63];
        long tb = (long)tile * 4096;
#pragma unroll
        for (int c = c0; c < c0 + 16; c++) {
            Wg_[tb + row*64 + c] = f2bf(WU[row][c]);
            U_ [tb + row*64 + c] = WU[row][64 + c];
            Qg_[tb + row*64 + c] = f2bf(gt * bf2f(Qb[row][c]));
            KpT_[tb + row*64 + c] = f2bf(expf(lge - lgS[c]) * bf2f(Kb[c][row]));
        }
        if (tid == 0) gend_[tile] = expf(lge);
    }
}

// ---------------------------------------------------------------- Phase B: sequential chunk scan
__global__ __launch_bounds__(256) void chunk_scan_k(
    const u16* __restrict__ Wg_, const u16* __restrict__ Amat_, const u16* __restrict__ Qg_,
    const u16* __restrict__ KpT_, const float* __restrict__ U_, const float* __restrict__ gend_,
    u16* __restrict__ oact)
{
    __shared__ float Sl[64][68];
    __shared__ u16   CT[64][72];
    const int bh = blockIdx.x, b = bh >> 4, h = bh & 15;
    const int tid = threadIdx.x, lane = tid & 63, wv = tid >> 6;
    const int lm = lane & 15, lg = lane >> 4;

    for (int i = tid; i < 64*68; i += 256) (&Sl[0][0])[i] = 0.f;
    __syncthreads();

    for (int n = 0; n < 32; n++) {
        const long tb = ((long)(bh*32 + n)) << 12;
        const int ar = 16*wv + lm;
        bf16x8_t Wa0 = *(const bf16x8_t*)(Wg_  + tb + ar*64 + 8*lg);
        bf16x8_t Wa1 = *(const bf16x8_t*)(Wg_  + tb + ar*64 + 32 + 8*lg);
        bf16x8_t Qa0 = *(const bf16x8_t*)(Qg_  + tb + ar*64 + 8*lg);
        bf16x8_t Qa1 = *(const bf16x8_t*)(Qg_  + tb + ar*64 + 32 + 8*lg);
        bf16x8_t Aa0 = *(const bf16x8_t*)(Amat_+ tb + ar*64 + 8*lg);
        bf16x8_t Aa1 = *(const bf16x8_t*)(Amat_+ tb + ar*64 + 32 + 8*lg);
        bf16x8_t Kp[4][2];
#pragma unroll
        for (int nt=0; nt<4; nt++)
#pragma unroll
            for (int sh=0; sh<2; sh++)
                Kp[nt][sh] = *(const bf16x8_t*)(KpT_ + tb + (16*nt+lm)*64 + 32*sh + 8*lg);
        float Uv[4][4];
#pragma unroll
        for (int nt=0; nt<4; nt++)
#pragma unroll
            for (int r=0; r<4; r++)
                Uv[nt][r] = U_[tb + (16*wv + 4*lg + r)*64 + 16*nt + lm];
        const float ge = gend_[bh*32 + n];

        bf16x8_t Shi[4][2], Slo[4][2];
#pragma unroll
        for (int nt=0; nt<4; nt++)
#pragma unroll
            for (int kh=0; kh<2; kh++){
                const float* sp = &Sl[16*nt + lm][32*kh + 8*lg];
                float4 aa = *(const float4*)sp;
                float4 bb = *(const float4*)(sp + 4);
                float xs[8] = {aa.x,aa.y,aa.z,aa.w,bb.x,bb.y,bb.z,bb.w};
#pragma unroll
                for (int j=0; j<8; j++){
                    u16 hv = f2bf(xs[j]);
                    Shi[nt][kh][j] = (short)hv;
                    Slo[nt][kh][j] = (short)f2bf(xs[j] - bf2f(hv));
                }
            }
        float Sa[4][4];
#pragma unroll
        for (int nt=0; nt<4; nt++)
#pragma unroll
            for (int r=0; r<4; r++)
                Sa[nt][r] = Sl[16*wv + 4*lg + r][16*nt + lm];

        // P = W * S^T (hi+lo)
        f32x4 accP[4];
#pragma unroll
        for (int nt=0; nt<4; nt++){
            accP[nt] = (f32x4){0,0,0,0};
            accP[nt] = MF(Wa0, Shi[nt][0], accP[nt]);
            accP[nt] = MF(Wa0, Slo[nt][0], accP[nt]);
            accP[nt] = MF(Wa1, Shi[nt][1], accP[nt]);
            accP[nt] = MF(Wa1, Slo[nt][1], accP[nt]);
        }
        // C = U - P -> CT (bf16, transposed)
#pragma unroll
        for (int nt=0; nt<4; nt++)
#pragma unroll
            for (int r=0; r<4; r++)
                CT[16*nt + lm][16*wv + 4*lg + r] = f2bf(Uv[nt][r] - accP[nt][r]);
        // O1 = gam*Q * S^T (hi+lo)
        f32x4 accO[4];
#pragma unroll
        for (int nt=0; nt<4; nt++){
            accO[nt] = (f32x4){0,0,0,0};
            accO[nt] = MF(Qa0, Shi[nt][0], accO[nt]);
            accO[nt] = MF(Qa0, Slo[nt][0], accO[nt]);
            accO[nt] = MF(Qa1, Shi[nt][1], accO[nt]);
            accO[nt] = MF(Qa1, Slo[nt][1], accO[nt]);
        }
        __syncthreads();   // CT complete; S reads complete

        // O2 = Amat * C^T
#pragma unroll
        for (int nt=0; nt<4; nt++){
            bf16x8_t C0 = *(const bf16x8_t*)&CT[16*nt + lm][8*lg];
            bf16x8_t C1 = *(const bf16x8_t*)&CT[16*nt + lm][32 + 8*lg];
            accO[nt] = MF(Aa0, C0, accO[nt]);
            accO[nt] = MF(Aa1, C1, accO[nt]);
        }
        // S' = gend*S + Kp'^T C
        bf16x8_t CTa0 = *(const bf16x8_t*)&CT[16*wv + lm][8*lg];
        bf16x8_t CTa1 = *(const bf16x8_t*)&CT[16*wv + lm][32 + 8*lg];
        f32x4 accS[4];
#pragma unroll
        for (int nt=0; nt<4; nt++){
            accS[nt] = (f32x4){ge*Sa[nt][0], ge*Sa[nt][1], ge*Sa[nt][2], ge*Sa[nt][3]};
            accS[nt] = MF(CTa0, Kp[nt][0], accS[nt]);
            accS[nt] = MF(CTa1, Kp[nt][1], accS[nt]);
        }
#pragma unroll
        for (int nt=0; nt<4; nt++)
#pragma unroll
            for (int r=0; r<4; r++)
                Sl[16*wv + 4*lg + r][16*nt + lm] = accS[nt][r];
        const int trow = n*64 + 16*wv + 4*lg;
#pragma unroll
        for (int nt=0; nt<4; nt++)
#pragma unroll
            for (int r=0; r<4; r++)
                oact[(long)(b*Tsz + trow + r)*1024 + h*64 + 16*nt + lm] = f2bf(accO[nt][r]);
        __syncthreads();
    }
}

// ---------------------------------------------------------------- epilogue: +Dp*v, rmsnorm, silu, gate
__global__ __launch_bounds__(256) void epi2_k(
    u16* __restrict__ o, const u16* __restrict__ g, const float* __restrict__ vc,
    const float* __restrict__ Dp, const float* __restrict__ onw)
{
    long row = (long)blockIdx.x * 4 + (threadIdx.x >> 6);
    int lane = threadIdx.x & 63;
    int h = (int)(row & 15);
    long idx = (row << 6) + lane;
    float ov = bf2f(o[idx]) + Dp[h] * vc[idx];
    float gv = bf2f(g[idx]);
    float ss = ov * ov;
#pragma unroll
    for (int off = 1; off < 64; off <<= 1) ss += __shfl_xor(ss, off);
    float r   = rsqrtf(ss * (1.f / 64.f) + 1e-6f);
    float on  = onw[lane] * (ov * r);
    float sil = on / (1.f + expf(-on));
    o[idx] = f2bf(gv * sil);
}

// ---------------------------------------------------------------- host launch
extern "C" void kernel_launch(void* const* d_in, const int* in_sizes, int n_in,
                              void* d_out, int out_size, void* d_ws, size_t ws_size,
                              hipStream_t stream)
{
    const float* x    = (const float*)d_in[0];
    const float* Wq   = (const float*)d_in[1];
    const float* Wk   = (const float*)d_in[2];
    const float* Wv   = (const float*)d_in[3];
    const float* Wg   = (const float*)d_in[4];
    const float* Wo   = (const float*)d_in[5];
    const float* Wb   = (const float*)d_in[6];
    const float* bb   = (const float*)d_in[7];
    const float* Wgk  = (const float*)d_in[8];
    const float* bgk  = (const float*)d_in[9];
    const float* cqw  = (const float*)d_in[10];
    const float* cqb  = (const float*)d_in[11];
    const float* ckw  = (const float*)d_in[12];
    const float* ckb  = (const float*)d_in[13];
    const float* cvw  = (const float*)d_in[14];
    const float* cvb  = (const float*)d_in[15];
    const float* A_log= (const float*)d_in[16];
    const float* Dp   = (const float*)d_in[17];
    const float* dtb  = (const float*)d_in[18];
    const float* onw  = (const float*)d_in[19];
    float* out = (float*)d_out;

    char* p = (char*)d_ws;
    auto alloc = [&](size_t bytes) -> char* {
        char* r = p; p += (bytes + 255) & ~(size_t)255; return r;
    };
    const size_t NBT = (size_t)BT * Csz;          // 4M elements
    const size_t NTILE = (size_t)32 * 32;         // 1024 chunk tiles
    u16*   xbf   = (u16*)  alloc(NBT * 2);
    u16*   wcat  = (u16*)  alloc((size_t)4 * Csz * Csz * 2);  // [Wq;Wk;Wv;Wg] bf16, contiguous
    u16*   Wobf  = (u16*)  alloc((size_t)Csz * Csz * 2);
    u16*   qkvg  = (u16*)  alloc((size_t)4 * NBT * 2);        // qpre|kpre|vpre|gbf contiguous
    float* qconv = (float*)alloc(NBT * 4);
    float* kconv = (float*)alloc(NBT * 4);
    float* ctab  = (float*)alloc((size_t)Tsz * 16 * 4);
    float* stab  = (float*)alloc((size_t)Tsz * 16 * 4);
    float* lalpha= (float*)alloc((size_t)BT * Hsz * 4);
    float* beta  = (float*)alloc((size_t)BT * Hsz * 4);
    u16*   Wg_t  = (u16*)  alloc(NTILE * 4096 * 2);
    u16*   Amat_t= (u16*)  alloc(NTILE * 4096 * 2);
    u16*   Qg_t  = (u16*)  alloc(NTILE * 4096 * 2);
    u16*   KpT_t = (u16*)  alloc(NTILE * 4096 * 2);
    float* U_t   = (float*)alloc(NTILE * 4096 * 4);
    float* gend_t= (float*)alloc(NTILE * 4);

    u16* Wqbf = wcat;
    u16* Wkbf = wcat + (size_t)Csz * Csz;
    u16* Wvbf = wcat + (size_t)2 * Csz * Csz;
    u16* Wgbf = wcat + (size_t)3 * Csz * Csz;
    u16* qpre = qkvg;
    u16* vpre = qkvg + 2 * NBT;
    u16* gbf  = qkvg + 3 * NBT;
    // overlays (stream-ordered reuse of dead buffers):
    float* vconv = (float*)qpre;   // 16MB over qpre+kpre (dead after conv_q/conv_k)
    u16*   oact  = (u16*)vpre;     // 8MB over vpre (dead after conv_v)

    // 1. rope tables
    rope_tables_k<<<(Tsz * 16 + 255) / 256, 256, 0, stream>>>(ctab, stab);

    // 2. f32 -> bf16 conversions
    cvt_f32_bf16_k<<<(int)(NBT / 4 + 255) / 256, 256, 0, stream>>>(x,  xbf,  (int)NBT);
    cvt_f32_bf16_k<<<(Csz * Csz / 4 + 255) / 256, 256, 0, stream>>>(Wq, Wqbf, Csz * Csz);
    cvt_f32_bf16_k<<<(Csz * Csz / 4 + 255) / 256, 256, 0, stream>>>(Wk, Wkbf, Csz * Csz);
    cvt_f32_bf16_k<<<(Csz * Csz / 4 + 255) / 256, 256, 0, stream>>>(Wv, Wvbf, Csz * Csz);
    cvt_f32_bf16_k<<<(Csz * Csz / 4 + 255) / 256, 256, 0, stream>>>(Wg, Wgbf, Csz * Csz);
    cvt_f32_bf16_k<<<(Csz * Csz / 4 + 255) / 256, 256, 0, stream>>>(Wo, Wobf, Csz * Csz);

    // 3. fused QKVG projection: M=4096, N=4096 over contiguous weights, split-store
    gemm_bf16_nt<<<32 * 32, 256, 0, stream>>>(xbf, wcat, nullptr, qkvg, 32, (long)NBT, Csz);

    // 4. depthwise conv + silu (f32 out)
    dim3 cgrid(Bsz * (Tsz / 64), Csz / 256);
    conv_silu_k<<<cgrid, 256, 0, stream>>>(qpre,            cqw, cqb, qconv);
    conv_silu_k<<<cgrid, 256, 0, stream>>>(qkvg + NBT,      ckw, ckb, kconv);
    conv_silu_k<<<cgrid, 256, 0, stream>>>(vpre,            cvw, cvb, vconv);

    // 5. rope + l2norm, in place on q/k
    rope_l2norm_k<<<(Bsz * Tsz * Hsz) / 4, 256, 0, stream>>>(qconv, ctab, stab);
    rope_l2norm_k<<<(Bsz * Tsz * Hsz) / 4, 256, 0, stream>>>(kconv, ctab, stab);

    // 6. beta / log-alpha
    ab_k<<<BT, 256, 0, stream>>>(x, Wb, bb, Wgk, bgk, A_log, dtb, lalpha, beta);

    // 7a. chunk precompute (parallel over 1024 tiles)
    chunk_prep_k<<<1024, 256, 0, stream>>>(qconv, kconv, vconv, lalpha, beta,
                                           Wg_t, Amat_t, Qg_t, KpT_t, U_t, gend_t);

    // 7b. sequential chunk scan (32 blocks)
    chunk_scan_k<<<Bsz * Hsz, 256, 0, stream>>>(Wg_t, Amat_t, Qg_t, KpT_t, U_t, gend_t, oact);

    // 8. epilogue: D-skip + rmsnorm + silu + gate, in place on oact
    epi2_k<<<(BT * Hsz) / 4, 256, 0, stream>>>(oact, gbf, vconv, Dp, onw);

    // 9. output projection (f32 -> d_out)
    gemm_bf16_nt<<<32 * 8, 256, 0, stream>>>(oact, Wobf, out, nullptr, 32, 0L, Csz);

    (void)in_sizes; (void)n_in; (void)out_size; (void)ws_size;
}

// Round 7
// 448.084 us; speedup vs baseline: 14.6415x; 1.2166x over previous
//
#include <hip/hip_runtime.h>

#define Bsz 2
#define Tsz 2048
#define Csz 1024
#define Hsz 16
#define Dsz 64
#define BT (Bsz*Tsz)   // 4096

typedef unsigned short u16;
typedef __attribute__((ext_vector_type(8))) short bf16x8_t;
typedef __attribute__((ext_vector_type(4))) float f32x4;
typedef __attribute__((ext_vector_type(4))) unsigned short us4;

#define MF(a,b,c) __builtin_amdgcn_mfma_f32_16x16x32_bf16(a,b,c,0,0,0)

__device__ __forceinline__ float bf2f(u16 u){
    union { unsigned i; float f; } c; c.i = ((unsigned)u) << 16; return c.f;
}
__device__ __forceinline__ u16 f2bf(float f){
    union { float f; unsigned i; } c; c.f = f;
    unsigned i = c.i;
    unsigned r = (i + 0x7fffu + ((i >> 16) & 1u)) >> 16;
    return (u16)r;
}
__device__ __forceinline__ void gload_lds16(const void* g, void* l){
    __builtin_amdgcn_global_load_lds(
        (const __attribute__((address_space(1))) unsigned int*)g,
        (__attribute__((address_space(3))) unsigned int*)l, 16, 0, 0);
}

// ---------------------------------------------------------------- rope tables
__global__ void rope_tables_k(float* __restrict__ ctab, float* __restrict__ stab){
    int idx = blockIdx.x * blockDim.x + threadIdx.x;
    if (idx >= Tsz * 16) return;
    int t = idx >> 4, m = idx & 15;
    float arf = (float)m / 16.f;                   // ar[i]=i/32, i=2m
    double sb = 10000.0 * pow(32.0, 64.0 / 62.0);  // scaled_base
    float invf = (float)(1.0 / pow(sb, (double)arf));
    float fe   = (float)(1.0 / pow(10000.0, (double)arf));
    float wl   = 6.283185307179586f / fe;
    float ms   = fminf(fmaxf((wl - 1.0f) / 31.0f, 0.f), 1.f);
    float scale = 1.f + 31.f * ms;
    float freq = ((float)t / scale) * invf;
    ctab[idx] = cosf(freq);
    stab[idx] = sinf(freq);
}

// ---------------------------------------------------------------- f32 -> bf16
__global__ void cvt_f32_bf16_k(const float* __restrict__ in, u16* __restrict__ out, int n){
    int i = (blockIdx.x * blockDim.x + threadIdx.x) * 4;
    if (i >= n) return;
    float4 v = *(const float4*)(in + i);
    us4 o; o.x = f2bf(v.x); o.y = f2bf(v.y); o.z = f2bf(v.z); o.w = f2bf(v.w);
    *(us4*)(out + i) = o;
}

// ---------------------------------------------------------------- bf16 MFMA GEMM (LDS-staged, m97 structure)
// C = A * Bw^T; A: MxK row-major, Bw: NxK row-major. 128x128 tile, BK=32,
// double-buffered LDS via global_load_lds (16B/lane, linear lane->LDS map).
// 1D grid + bijective XCD swizzle (gridDim.x % 8 == 0).
// Store: Cf f32 [m*1024+col] if non-null; else bf16 split-store
//        Cb[(col>>10)*sstride + m*1024 + (col&1023)].
__global__ __launch_bounds__(256) void gemm_bf16_nt(
    const u16* __restrict__ A, const u16* __restrict__ Bw,
    float* __restrict__ Cf, u16* __restrict__ Cb,
    int gm, long sstride, int Kdim)
{
    __shared__ u16 As[2][128*32];
    __shared__ u16 Bs[2][128*32];

    const int nwg = gridDim.x;
    const int q8  = nwg >> 3;
    const int id  = blockIdx.x;
    const int swz = (id & 7) * q8 + (id >> 3);
    const int bx  = swz % gm;
    const int by  = swz / gm;

    const int tid = threadIdx.x;
    const int w  = tid >> 6, l = tid & 63;
    const int lm = l & 15,  lg = l >> 4;
    const int wm = (w >> 1) << 6;
    const int wn = (w & 1) << 6;

    // staging map: wave w stages 16-row chunks {w, w+4} of each 128x32 tile.
    // LDS byte offset = w*1024 + l*16 (+4096 for second chunk): linear in lane.
    const int r0  = (w << 4) + (l >> 2);     // rows 0..63
    const int kof = (l & 3) * 8;             // k sub-offset (elements)
    const long ga0 = (long)(bx * 128 + r0)      * Kdim + kof;
    const long ga1 = (long)(bx * 128 + r0 + 64) * Kdim + kof;
    const long gb0 = (long)(by * 128 + r0)      * Kdim + kof;
    const long gb1 = (long)(by * 128 + r0 + 64) * Kdim + kof;
    const int  ldst = r0 * 32 + kof;         // element offset in [128][32]

    f32x4 acc[4][4];
#pragma unroll
    for (int i = 0; i < 4; i++)
#pragma unroll
        for (int j = 0; j < 4; j++) acc[i][j] = (f32x4){0.f, 0.f, 0.f, 0.f};

    const int nt = Kdim >> 5;
#define STAGE(B_, T_) do { int k0_ = (T_) << 5;                       \
        gload_lds16(A  + ga0 + k0_, &As[B_][ldst]);                   \
        gload_lds16(A  + ga1 + k0_, &As[B_][ldst + 2048]);            \
        gload_lds16(Bw + gb0 + k0_, &Bs[B_][ldst]);                   \
        gload_lds16(Bw + gb1 + k0_, &Bs[B_][ldst + 2048]);            \
    } while (0)

    STAGE(0, 0);
    __syncthreads();
    int buf = 0;
    for (int t = 0; t < nt; t++) {
        if (t + 1 < nt) STAGE(buf ^ 1, t + 1);
        bf16x8_t av[4], bv[4];
#pragma unroll
        for (int i = 0; i < 4; i++) av[i] = *(const bf16x8_t*)&As[buf][(wm + i*16 + lm)*32 + lg*8];
#pragma unroll
        for (int j = 0; j < 4; j++) bv[j] = *(const bf16x8_t*)&Bs[buf][(wn + j*16 + lm)*32 + lg*8];
#pragma unroll
        for (int i = 0; i < 4; i++)
#pragma unroll
            for (int j = 0; j < 4; j++)
                acc[i][j] = MF(av[i], bv[j], acc[i][j]);
        __syncthreads();
        buf ^= 1;
    }
#undef STAGE

    const int crow0 = bx * 128 + wm + lg * 4;
    const int ccol0 = by * 128 + wn + lm;
#pragma unroll
    for (int i = 0; i < 4; i++)
#pragma unroll
        for (int j = 0; j < 4; j++)
#pragma unroll
            for (int r = 0; r < 4; r++) {
                long row = crow0 + i * 16 + r;
                int  col = ccol0 + j * 16;
                float vv = acc[i][j][r];
                if (Cf) Cf[row * 1024 + col] = vv;
                else    Cb[(long)(col >> 10) * sstride + row * 1024 + (col & 1023)] = f2bf(vv);
            }
}

// ---------------------------------------------------------------- depthwise conv K=4 + silu
__global__ __launch_bounds__(256) void conv_silu_k(
    const u16* __restrict__ pre, const float* __restrict__ w,
    const float* __restrict__ bias, float* __restrict__ out)
{
    int c  = blockIdx.y * 256 + threadIdx.x;
    int bi = blockIdx.x;              // B * (T/64)
    int b  = bi >> 5;
    int t0 = (bi & 31) << 6;
    float w0 = w[c*4+0], w1 = w[c*4+1], w2 = w[c*4+2], w3 = w[c*4+3];
    float bs = bias[c];
    long base = ((long)b * Tsz) * Csz + c;
    float xm3 = (t0 >= 3) ? bf2f(pre[base + (long)(t0-3)*Csz]) : 0.f;
    float xm2 = (t0 >= 2) ? bf2f(pre[base + (long)(t0-2)*Csz]) : 0.f;
    float xm1 = (t0 >= 1) ? bf2f(pre[base + (long)(t0-1)*Csz]) : 0.f;
    for (int t = t0; t < t0 + 64; t++) {
        float xc = bf2f(pre[base + (long)t * Csz]);
        float z  = bs + w0*xm3 + w1*xm2 + w2*xm1 + w3*xc;
        out[base + (long)t * Csz] = z / (1.f + expf(-z));
        xm3 = xm2; xm2 = xm1; xm1 = xc;
    }
}

// ---------------------------------------------------------------- rope + l2norm (in-place, f32)
__global__ __launch_bounds__(256) void rope_l2norm_k(
    float* __restrict__ qk, const float* __restrict__ ctab, const float* __restrict__ stab)
{
    int row = blockIdx.x * 4 + (threadIdx.x >> 6);
    int j   = threadIdx.x & 63;
    int t   = (row >> 4) & (Tsz - 1);
    int p   = j & 31, m = j & 15, hi = j >> 5;
    float2 xv = *(const float2*)(qk + (long)row * 64 + p * 2);
    float c = ctab[t * 16 + m], s = stab[t * 16 + m];
    float val = hi ? (xv.x * s + xv.y * c) : (xv.x * c - xv.y * s);
    float ss = val * val;
#pragma unroll
    for (int off = 1; off < 64; off <<= 1) ss += __shfl_xor(ss, off);
    float inv = 1.f / fmaxf(sqrtf(ss), 1e-12f);
    qk[(long)row * 64 + j] = val * inv;
}

// ---------------------------------------------------------------- beta / log-alpha
__global__ __launch_bounds__(256) void ab_k(
    const float* __restrict__ x,
    const float* __restrict__ Wb,  const float* __restrict__ bb,
    const float* __restrict__ Wgk, const float* __restrict__ bgk,
    const float* __restrict__ A_log, const float* __restrict__ dtb,
    float* __restrict__ lalpha, float* __restrict__ beta)
{
    __shared__ float xr[1024];
    int bt = blockIdx.x;
    const float* xp = x + (long)bt * 1024;
#pragma unroll
    for (int i = 0; i < 4; i++) xr[threadIdx.x + i * 256] = xp[threadIdx.x + i * 256];
    __syncthreads();
    int wv = threadIdx.x >> 6, l = threadIdx.x & 63;
#pragma unroll
    for (int oo = 0; oo < 8; oo++) {
        int o = wv * 8 + oo;           // 0..15: beta, 16..31: lalpha
        int h = o & 15;
        const float* wr = (o < 16 ? Wb : Wgk) + (long)h * 1024;
        float p = 0.f;
#pragma unroll
        for (int i = 0; i < 16; i++) p += wr[l + i * 64] * xr[l + i * 64];
        for (int off = 32; off; off >>= 1) p += __shfl_xor(p, off);
        if (l == 0) {
            if (o < 16) {
                beta[bt * 16 + h] = 1.f / (1.f + expf(-(p + bb[h])));
            } else {
                float gk = p + bgk[h] + dtb[h];
                float sp = gk > 0.f ? gk + log1pf(expf(-gk)) : log1pf(expf(gk));
                lalpha[bt * 16 + h] = -expf(A_log[h]) * sp;   // log(alpha)
            }
        }
    }
}

// ---------------------------------------------------------------- Phase A: per-chunk WY precompute
__global__ __launch_bounds__(256) void chunk_prep_k(
    const float* __restrict__ q, const float* __restrict__ k, const float* __restrict__ v,
    const float* __restrict__ lalpha, const float* __restrict__ beta,
    u16* __restrict__ Wg_, u16* __restrict__ Amat_, u16* __restrict__ Qg_,
    u16* __restrict__ KpT_, float* __restrict__ U_, float* __restrict__ gend_)
{
    __shared__ u16   Kb[64][72];
    __shared__ u16   Qb[64][72];
    __shared__ float Lm[64][68];
    __shared__ float WU[64][132];
    __shared__ float lgS[64];
    __shared__ float betaS[64];

    const int tile = blockIdx.x;
    const int bh = tile >> 5, n = tile & 31;
    const int b = bh >> 4, h = bh & 15;
    const int t0 = n << 6;
    const int tid = threadIdx.x;
    const int lane = tid & 63, wv = tid >> 6;
    const int lm = lane & 15, lg = lane >> 4;

    // log-gamma inclusive scan + beta staging (wave 0)
    if (wv == 0) {
        long rix = ((long)(b * Tsz + t0 + lane)) * Hsz + h;
        float lgv = lalpha[rix];
#pragma unroll
        for (int off = 1; off < 64; off <<= 1) {
            float u = __shfl_up(lgv, off);
            if (lane >= off) lgv += u;
        }
        lgS[lane] = lgv;
        betaS[lane] = beta[rix];
    }
    // load K,Q tiles -> bf16 LDS
    {
        int row = tid >> 2, c0 = (tid & 3) << 4;
        long gb = ((long)(b * Tsz + t0 + row) * Hsz + h) << 6;
#pragma unroll
        for (int j = 0; j < 4; j++) {
            float4 kk = *(const float4*)(k + gb + c0 + 4*j);
            float4 qq = *(const float4*)(q + gb + c0 + 4*j);
            us4 kw, qw;
            kw.x=f2bf(kk.x); kw.y=f2bf(kk.y); kw.z=f2bf(kk.z); kw.w=f2bf(kk.w);
            qw.x=f2bf(qq.x); qw.y=f2bf(qq.y); qw.z=f2bf(qq.z); qw.w=f2bf(qq.w);
            *(us4*)&Kb[row][c0 + 4*j] = kw;
            *(us4*)&Qb[row][c0 + 4*j] = qw;
        }
    }
    __syncthreads();

    // Mkk, Mqk via MFMA; scaled L (f32 LDS) and Amat (bf16 global)
    {
        const int ar = 16*wv + lm;
        bf16x8_t Ka0 = *(const bf16x8_t*)&Kb[ar][8*lg];
        bf16x8_t Ka1 = *(const bf16x8_t*)&Kb[ar][32 + 8*lg];
        bf16x8_t Qa0 = *(const bf16x8_t*)&Qb[ar][8*lg];
        bf16x8_t Qa1 = *(const bf16x8_t*)&Qb[ar][32 + 8*lg];
        f32x4 aKK[4], aQK[4];
#pragma unroll
        for (int nt=0; nt<4; nt++){ aKK[nt]=(f32x4){0,0,0,0}; aQK[nt]=(f32x4){0,0,0,0}; }
#pragma unroll
        for (int nt=0; nt<4; nt++){
            int br = 16*nt + lm;
            bf16x8_t B0 = *(const bf16x8_t*)&Kb[br][8*lg];
            bf16x8_t B1 = *(const bf16x8_t*)&Kb[br][32 + 8*lg];
            aKK[nt] = MF(Ka0, B0, aKK[nt]); aKK[nt] = MF(Ka1, B1, aKK[nt]);
            aQK[nt] = MF(Qa0, B0, aQK[nt]); aQK[nt] = MF(Qa1, B1, aQK[nt]);
        }
#pragma unroll
        for (int r=0; r<4; r++){
            int t = 16*wv + 4*lg + r;
            float lgt = lgS[t];
            float bt = betaS[t];
#pragma unroll
            for (int nt=0; nt<4; nt++){
                int s = 16*nt + lm;
                float ratio = expf(lgt - lgS[s]);
                Lm[t][s] = (s < t) ? bt * ratio * aKK[nt][r] : 0.f;
                Amat_[(long)tile*4096 + t*64 + s] = f2bf((s <= t) ? ratio * aQK[nt][r] : 0.f);
            }
        }
    }
    // init WU = [diag(b*gamma)K | diag(b)V]  (f32, from global)
    {
        int row = tid >> 2, qd = tid & 3;
        long gb = ((long)(b * Tsz + t0 + row) * Hsz + h) << 6;
        float bt = betaS[row];
        float gt = expf(lgS[row]);
        if (qd < 2) {
            int c0 = qd * 32;
            float bg = bt * gt;
#pragma unroll
            for (int j = 0; j < 8; j++) {
                float4 kk = *(const float4*)(k + gb + c0 + 4*j);
                WU[row][c0+4*j+0] = bg*kk.x; WU[row][c0+4*j+1] = bg*kk.y;
                WU[row][c0+4*j+2] = bg*kk.z; WU[row][c0+4*j+3] = bg*kk.w;
            }
        } else {
            int c0 = (qd - 2) * 32;
#pragma unroll
            for (int j = 0; j < 8; j++) {
                float4 vv = *(const float4*)(v + gb + c0 + 4*j);
                WU[row][64+c0+4*j+0] = bt*vv.x; WU[row][64+c0+4*j+1] = bt*vv.y;
                WU[row][64+c0+4*j+2] = bt*vv.z; WU[row][64+c0+4*j+3] = bt*vv.w;
            }
        }
    }
    __syncthreads();

    // forward substitution: (I+L) X = rhs, column-owned, X in registers.
    if (tid < 128) {
        float X[64];
        X[0] = WU[0][tid];
#pragma unroll
        for (int r = 1; r < 64; r++) {
            float a0 = 0.f, a1 = 0.f, a2 = 0.f, a3 = 0.f;
            const float4* L4 = (const float4*)&Lm[r][0];
#pragma unroll
            for (int j = 0; 4*j < r; j++) {
                float4 lv = L4[j];                // wave-uniform broadcast read
                int s = 4*j;
                a0 += lv.x * X[s];
                if (s+1 < r) a1 += lv.y * X[s+1];
                if (s+2 < r) a2 += lv.z * X[s+2];
                if (s+3 < r) a3 += lv.w * X[s+3];
            }
            X[r] = WU[r][tid] - ((a0+a1)+(a2+a3));
        }
#pragma unroll
        for (int r = 0; r < 64; r++) WU[r][tid] = X[r];
    }
    __syncthreads();

    // outputs
    {
        int row = tid >> 2, c0 = (tid & 3) << 4;
        float gt  = expf(lgS[row]);
        float lge = lgS[63];
        long tb = (long)tile * 4096;
#pragma unroll
        for (int c = c0; c < c0 + 16; c++) {
            Wg_[tb + row*64 + c] = f2bf(WU[row][c]);
            U_ [tb + row*64 + c] = WU[row][64 + c];
            Qg_[tb + row*64 + c] = f2bf(gt * bf2f(Qb[row][c]));
            KpT_[tb + row*64 + c] = f2bf(expf(lge - lgS[c]) * bf2f(Kb[c][row]));
        }
        if (tid == 0) gend_[tile] = expf(lge);
    }
}

// ---------------------------------------------------------------- Phase B: sequential chunk scan
__global__ __launch_bounds__(256) void chunk_scan_k(
    const u16* __restrict__ Wg_, const u16* __restrict__ Amat_, const u16* __restrict__ Qg_,
    const u16* __restrict__ KpT_, const float* __restrict__ U_, const float* __restrict__ gend_,
    u16* __restrict__ oact)
{
    __shared__ float Sl[64][68];
    __shared__ u16   CT[64][72];
    const int bh = blockIdx.x, b = bh >> 4, h = bh & 15;
    const int tid = threadIdx.x, lane = tid & 63, wv = tid >> 6;
    const int lm = lane & 15, lg = lane >> 4;

    for (int i = tid; i < 64*68; i += 256) (&Sl[0][0])[i] = 0.f;
    __syncthreads();

    for (int n = 0; n < 32; n++) {
        const long tb = ((long)(bh*32 + n)) << 12;
        const int ar = 16*wv + lm;
        bf16x8_t Wa0 = *(const bf16x8_t*)(Wg_  + tb + ar*64 + 8*lg);
        bf16x8_t Wa1 = *(const bf16x8_t*)(Wg_  + tb + ar*64 + 32 + 8*lg);
        bf16x8_t Qa0 = *(const bf16x8_t*)(Qg_  + tb + ar*64 + 8*lg);
        bf16x8_t Qa1 = *(const bf16x8_t*)(Qg_  + tb + ar*64 + 32 + 8*lg);
        bf16x8_t Aa0 = *(const bf16x8_t*)(Amat_+ tb + ar*64 + 8*lg);
        bf16x8_t Aa1 = *(const bf16x8_t*)(Amat_+ tb + ar*64 + 32 + 8*lg);
        bf16x8_t Kp[4][2];
#pragma unroll
        for (int nt=0; nt<4; nt++)
#pragma unroll
            for (int sh=0; sh<2; sh++)
                Kp[nt][sh] = *(const bf16x8_t*)(KpT_ + tb + (16*nt+lm)*64 + 32*sh + 8*lg);
        float Uv[4][4];
#pragma unroll
        for (int nt=0; nt<4; nt++)
#pragma unroll
            for (int r=0; r<4; r++)
                Uv[nt][r] = U_[tb + (16*wv + 4*lg + r)*64 + 16*nt + lm];
        const float ge = gend_[bh*32 + n];

        bf16x8_t Shi[4][2], Slo[4][2];
#pragma unroll
        for (int nt=0; nt<4; nt++)
#pragma unroll
            for (int kh=0; kh<2; kh++){
                const float* sp = &Sl[16*nt + lm][32*kh + 8*lg];
                float4 aa = *(const float4*)sp;
                float4 bb = *(const float4*)(sp + 4);
                float xs[8] = {aa.x,aa.y,aa.z,aa.w,bb.x,bb.y,bb.z,bb.w};
#pragma unroll
                for (int j=0; j<8; j++){
                    u16 hv = f2bf(xs[j]);
                    Shi[nt][kh][j] = (short)hv;
                    Slo[nt][kh][j] = (short)f2bf(xs[j] - bf2f(hv));
                }
            }
        float Sa[4][4];
#pragma unroll
        for (int nt=0; nt<4; nt++)
#pragma unroll
            for (int r=0; r<4; r++)
                Sa[nt][r] = Sl[16*wv + 4*lg + r][16*nt + lm];

        // P = W * S^T (hi+lo)
        f32x4 accP[4];
#pragma unroll
        for (int nt=0; nt<4; nt++){
            accP[nt] = (f32x4){0,0,0,0};
            accP[nt] = MF(Wa0, Shi[nt][0], accP[nt]);
            accP[nt] = MF(Wa0, Slo[nt][0], accP[nt]);
            accP[nt] = MF(Wa1, Shi[nt][1], accP[nt]);
            accP[nt] = MF(Wa1, Slo[nt][1], accP[nt]);
        }
        // C = U - P -> CT (bf16, transposed)
#pragma unroll
        for (int nt=0; nt<4; nt++)
#pragma unroll
            for (int r=0; r<4; r++)
                CT[16*nt + lm][16*wv + 4*lg + r] = f2bf(Uv[nt][r] - accP[nt][r]);
        // O1 = gam*Q * S^T (hi+lo)
        f32x4 accO[4];
#pragma unroll
        for (int nt=0; nt<4; nt++){
            accO[nt] = (f32x4){0,0,0,0};
            accO[nt] = MF(Qa0, Shi[nt][0], accO[nt]);
            accO[nt] = MF(Qa0, Slo[nt][0], accO[nt]);
            accO[nt] = MF(Qa1, Shi[nt][1], accO[nt]);
            accO[nt] = MF(Qa1, Slo[nt][1], accO[nt]);
        }
        __syncthreads();   // CT complete; S reads complete

        // O2 = Amat * C^T
#pragma unroll
        for (int nt=0; nt<4; nt++){
            bf16x8_t C0 = *(const bf16x8_t*)&CT[16*nt + lm][8*lg];
            bf16x8_t C1 = *(const bf16x8_t*)&CT[16*nt + lm][32 + 8*lg];
            accO[nt] = MF(Aa0, C0, accO[nt]);
            accO[nt] = MF(Aa1, C1, accO[nt]);
        }
        // S' = gend*S + Kp'^T C
        bf16x8_t CTa0 = *(const bf16x8_t*)&CT[16*wv + lm][8*lg];
        bf16x8_t CTa1 = *(const bf16x8_t*)&CT[16*wv + lm][32 + 8*lg];
        f32x4 accS[4];
#pragma unroll
        for (int nt=0; nt<4; nt++){
            accS[nt] = (f32x4){ge*Sa[nt][0], ge*Sa[nt][1], ge*Sa[nt][2], ge*Sa[nt][3]};
            accS[nt] = MF(CTa0, Kp[nt][0], accS[nt]);
            accS[nt] = MF(CTa1, Kp[nt][1], accS[nt]);
        }
#pragma unroll
        for (int nt=0; nt<4; nt++)
#pragma unroll
            for (int r=0; r<4; r++)
                Sl[16*wv + 4*lg + r][16*nt + lm] = accS[nt][r];
        const int trow = n*64 + 16*wv + 4*lg;
#pragma unroll
        for (int nt=0; nt<4; nt++)
#pragma unroll
            for (int r=0; r<4; r++)
                oact[(long)(b*Tsz + trow + r)*1024 + h*64 + 16*nt + lm] = f2bf(accO[nt][r]);
        __syncthreads();
    }
}

// ---------------------------------------------------------------- epilogue: +Dp*v, rmsnorm, silu, gate
__global__ __launch_bounds__(256) void epi2_k(
    u16* __restrict__ o, const u16* __restrict__ g, const float* __restrict__ vc,
    const float* __restrict__ Dp, const float* __restrict__ onw)
{
    long row = (long)blockIdx.x * 4 + (threadIdx.x >> 6);
    int lane = threadIdx.x & 63;
    int h = (int)(row & 15);
    long idx = (row << 6) + lane;
    float ov = bf2f(o[idx]) + Dp[h] * vc[idx];
    float gv = bf2f(g[idx]);
    float ss = ov * ov;
#pragma unroll
    for (int off = 1; off < 64; off <<= 1) ss += __shfl_xor(ss, off);
    float r   = rsqrtf(ss * (1.f / 64.f) + 1e-6f);
    float on  = onw[lane] * (ov * r);
    float sil = on / (1.f + expf(-on));
    o[idx] = f2bf(gv * sil);
}

// ---------------------------------------------------------------- host launch
extern "C" void kernel_launch(void* const* d_in, const int* in_sizes, int n_in,
                              void* d_out, int out_size, void* d_ws, size_t ws_size,
                              hipStream_t stream)
{
    const float* x    = (const float*)d_in[0];
    const float* Wq   = (const float*)d_in[1];
    const float* Wk   = (const float*)d_in[2];
    const float* Wv   = (const float*)d_in[3];
    const float* Wg   = (const float*)d_in[4];
    const float* Wo   = (const float*)d_in[5];
    const float* Wb   = (const float*)d_in[6];
    const float* bb   = (const float*)d_in[7];
    const float* Wgk  = (const float*)d_in[8];
    const float* bgk  = (const float*)d_in[9];
    const float* cqw  = (const float*)d_in[10];
    const float* cqb  = (const float*)d_in[11];
    const float* ckw  = (const float*)d_in[12];
    const float* ckb  = (const float*)d_in[13];
    const float* cvw  = (const float*)d_in[14];
    const float* cvb  = (const float*)d_in[15];
    const float* A_log= (const float*)d_in[16];
    const float* Dp   = (const float*)d_in[17];
    const float* dtb  = (const float*)d_in[18];
    const float* onw  = (const float*)d_in[19];
    float* out = (float*)d_out;

    char* p = (char*)d_ws;
    auto alloc = [&](size_t bytes) -> char* {
        char* r = p; p += (bytes + 255) & ~(size_t)255; return r;
    };
    const size_t NBT = (size_t)BT * Csz;          // 4M elements
    const size_t NTILE = (size_t)32 * 32;         // 1024 chunk tiles
    u16*   xbf   = (u16*)  alloc(NBT * 2);
    u16*   wcat  = (u16*)  alloc((size_t)4 * Csz * Csz * 2);  // [Wq;Wk;Wv;Wg] bf16, contiguous
    u16*   Wobf  = (u16*)  alloc((size_t)Csz * Csz * 2);
    u16*   qkvg  = (u16*)  alloc((size_t)4 * NBT * 2);        // qpre|kpre|vpre|gbf contiguous
    float* qconv = (float*)alloc(NBT * 4);
    float* kconv = (float*)alloc(NBT * 4);
    float* ctab  = (float*)alloc((size_t)Tsz * 16 * 4);
    float* stab  = (float*)alloc((size_t)Tsz * 16 * 4);
    float* lalpha= (float*)alloc((size_t)BT * Hsz * 4);
    float* beta  = (float*)alloc((size_t)BT * Hsz * 4);
    u16*   Wg_t  = (u16*)  alloc(NTILE * 4096 * 2);
    u16*   Amat_t= (u16*)  alloc(NTILE * 4096 * 2);
    u16*   Qg_t  = (u16*)  alloc(NTILE * 4096 * 2);
    u16*   KpT_t = (u16*)  alloc(NTILE * 4096 * 2);
    float* U_t   = (float*)alloc(NTILE * 4096 * 4);
    float* gend_t= (float*)alloc(NTILE * 4);

    u16* Wqbf = wcat;
    u16* Wkbf = wcat + (size_t)Csz * Csz;
    u16* Wvbf = wcat + (size_t)2 * Csz * Csz;
    u16* Wgbf = wcat + (size_t)3 * Csz * Csz;
    u16* qpre = qkvg;
    u16* vpre = qkvg + 2 * NBT;
    u16* gbf  = qkvg + 3 * NBT;
    // overlays (stream-ordered reuse of dead buffers):
    float* vconv = (float*)qpre;   // 16MB over qpre+kpre (dead after conv_q/conv_k)
    u16*   oact  = (u16*)vpre;     // 8MB over vpre (dead after conv_v)

    // 1. rope tables
    rope_tables_k<<<(Tsz * 16 + 255) / 256, 256, 0, stream>>>(ctab, stab);

    // 2. f32 -> bf16 conversions
    cvt_f32_bf16_k<<<(int)(NBT / 4 + 255) / 256, 256, 0, stream>>>(x,  xbf,  (int)NBT);
    cvt_f32_bf16_k<<<(Csz * Csz / 4 + 255) / 256, 256, 0, stream>>>(Wq, Wqbf, Csz * Csz);
    cvt_f32_bf16_k<<<(Csz * Csz / 4 + 255) / 256, 256, 0, stream>>>(Wk, Wkbf, Csz * Csz);
    cvt_f32_bf16_k<<<(Csz * Csz / 4 + 255) / 256, 256, 0, stream>>>(Wv, Wvbf, Csz * Csz);
    cvt_f32_bf16_k<<<(Csz * Csz / 4 + 255) / 256, 256, 0, stream>>>(Wg, Wgbf, Csz * Csz);
    cvt_f32_bf16_k<<<(Csz * Csz / 4 + 255) / 256, 256, 0, stream>>>(Wo, Wobf, Csz * Csz);

    // 3. fused QKVG projection: M=4096, N=4096 over contiguous weights, split-store
    gemm_bf16_nt<<<32 * 32, 256, 0, stream>>>(xbf, wcat, nullptr, qkvg, 32, (long)NBT, Csz);

    // 4. depthwise conv + silu (f32 out)
    dim3 cgrid(Bsz * (Tsz / 64), Csz / 256);
    conv_silu_k<<<cgrid, 256, 0, stream>>>(qpre,            cqw, cqb, qconv);
    conv_silu_k<<<cgrid, 256, 0, stream>>>(qkvg + NBT,      ckw, ckb, kconv);
    conv_silu_k<<<cgrid, 256, 0, stream>>>(vpre,            cvw, cvb, vconv);

    // 5. rope + l2norm, in place on q/k
    rope_l2norm_k<<<(Bsz * Tsz * Hsz) / 4, 256, 0, stream>>>(qconv, ctab, stab);
    rope_l2norm_k<<<(Bsz * Tsz * Hsz) / 4, 256, 0, stream>>>(kconv, ctab, stab);

    // 6. beta / log-alpha
    ab_k<<<BT, 256, 0, stream>>>(x, Wb, bb, Wgk, bgk, A_log, dtb, lalpha, beta);

    // 7a. chunk precompute (parallel over 1024 tiles)
    chunk_prep_k<<<1024, 256, 0, stream>>>(qconv, kconv, vconv, lalpha, beta,
                                           Wg_t, Amat_t, Qg_t, KpT_t, U_t, gend_t);

    // 7b. sequential chunk scan (32 blocks)
    chunk_scan_k<<<Bsz * Hsz, 256, 0, stream>>>(Wg_t, Amat_t, Qg_t, KpT_t, U_t, gend_t, oact);

    // 8. epilogue: D-skip + rmsnorm + silu + gate, in place on oact
    epi2_k<<<(BT * Hsz) / 4, 256, 0, stream>>>(oact, gbf, vconv, Dp, onw);

    // 9. output projection (f32 -> d_out)
    gemm_bf16_nt<<<32 * 8, 256, 0, stream>>>(oact, Wobf, out, nullptr, 32, 0L, Csz);

    (void)in_sizes; (void)n_in; (void)out_size; (void)ws_size;
}

// Round 8
// 416.082 us; speedup vs baseline: 15.7676x; 1.0769x over previous
//
#include <hip/hip_runtime.h>

#define Bsz 2
#define Tsz 2048
#define Csz 1024
#define Hsz 16
#define Dsz 64
#define BT (Bsz*Tsz)   // 4096

typedef unsigned short u16;
typedef __attribute__((ext_vector_type(8))) short bf16x8_t;
typedef __attribute__((ext_vector_type(4))) float f32x4;
typedef __attribute__((ext_vector_type(4))) unsigned short us4;

#define MF(a,b,c) __builtin_amdgcn_mfma_f32_16x16x32_bf16(a,b,c,0,0,0)

__device__ __forceinline__ float bf2f(u16 u){
    union { unsigned i; float f; } c; c.i = ((unsigned)u) << 16; return c.f;
}
__device__ __forceinline__ u16 f2bf(float f){
    union { float f; unsigned i; } c; c.f = f;
    unsigned i = c.i;
    unsigned r = (i + 0x7fffu + ((i >> 16) & 1u)) >> 16;
    return (u16)r;
}
__device__ __forceinline__ void gload_lds16(const void* g, void* l){
    __builtin_amdgcn_global_load_lds(
        (const __attribute__((address_space(1))) unsigned int*)g,
        (__attribute__((address_space(3))) unsigned int*)l, 16, 0, 0);
}

// ---------------------------------------------------------------- rope tables
__global__ void rope_tables_k(float* __restrict__ ctab, float* __restrict__ stab){
    int idx = blockIdx.x * blockDim.x + threadIdx.x;
    if (idx >= Tsz * 16) return;
    int t = idx >> 4, m = idx & 15;
    float arf = (float)m / 16.f;                   // ar[i]=i/32, i=2m
    double sb = 10000.0 * pow(32.0, 64.0 / 62.0);  // scaled_base
    float invf = (float)(1.0 / pow(sb, (double)arf));
    float fe   = (float)(1.0 / pow(10000.0, (double)arf));
    float wl   = 6.283185307179586f / fe;
    float ms   = fminf(fmaxf((wl - 1.0f) / 31.0f, 0.f), 1.f);
    float scale = 1.f + 31.f * ms;
    float freq = ((float)t / scale) * invf;
    ctab[idx] = cosf(freq);
    stab[idx] = sinf(freq);
}

// ---------------------------------------------------------------- f32 -> bf16
__global__ void cvt_f32_bf16_k(const float* __restrict__ in, u16* __restrict__ out, int n){
    int i = (blockIdx.x * blockDim.x + threadIdx.x) * 4;
    if (i >= n) return;
    float4 v = *(const float4*)(in + i);
    us4 o; o.x = f2bf(v.x); o.y = f2bf(v.y); o.z = f2bf(v.z); o.w = f2bf(v.w);
    *(us4*)(out + i) = o;
}

// ---------------------------------------------------------------- bf16 MFMA GEMM (LDS-staged, m97 structure)
__global__ __launch_bounds__(256) void gemm_bf16_nt(
    const u16* __restrict__ A, const u16* __restrict__ Bw,
    float* __restrict__ Cf, u16* __restrict__ Cb,
    int gm, long sstride, int Kdim)
{
    __shared__ u16 As[2][128*32];
    __shared__ u16 Bs[2][128*32];

    const int nwg = gridDim.x;
    const int q8  = nwg >> 3;
    const int id  = blockIdx.x;
    const int swz = (id & 7) * q8 + (id >> 3);
    const int bx  = swz % gm;
    const int by  = swz / gm;

    const int tid = threadIdx.x;
    const int w  = tid >> 6, l = tid & 63;
    const int lm = l & 15,  lg = l >> 4;
    const int wm = (w >> 1) << 6;
    const int wn = (w & 1) << 6;

    const int r0  = (w << 4) + (l >> 2);     // rows 0..63
    const int kof = (l & 3) * 8;             // k sub-offset (elements)
    const long ga0 = (long)(bx * 128 + r0)      * Kdim + kof;
    const long ga1 = (long)(bx * 128 + r0 + 64) * Kdim + kof;
    const long gb0 = (long)(by * 128 + r0)      * Kdim + kof;
    const long gb1 = (long)(by * 128 + r0 + 64) * Kdim + kof;
    const int  ldst = r0 * 32 + kof;         // element offset in [128][32]

    f32x4 acc[4][4];
#pragma unroll
    for (int i = 0; i < 4; i++)
#pragma unroll
        for (int j = 0; j < 4; j++) acc[i][j] = (f32x4){0.f, 0.f, 0.f, 0.f};

    const int nt = Kdim >> 5;
#define STAGE(B_, T_) do { int k0_ = (T_) << 5;                       \
        gload_lds16(A  + ga0 + k0_, &As[B_][ldst]);                   \
        gload_lds16(A  + ga1 + k0_, &As[B_][ldst + 2048]);            \
        gload_lds16(Bw + gb0 + k0_, &Bs[B_][ldst]);                   \
        gload_lds16(Bw + gb1 + k0_, &Bs[B_][ldst + 2048]);            \
    } while (0)

    STAGE(0, 0);
    __syncthreads();
    int buf = 0;
    for (int t = 0; t < nt; t++) {
        if (t + 1 < nt) STAGE(buf ^ 1, t + 1);
        bf16x8_t av[4], bv[4];
#pragma unroll
        for (int i = 0; i < 4; i++) av[i] = *(const bf16x8_t*)&As[buf][(wm + i*16 + lm)*32 + lg*8];
#pragma unroll
        for (int j = 0; j < 4; j++) bv[j] = *(const bf16x8_t*)&Bs[buf][(wn + j*16 + lm)*32 + lg*8];
#pragma unroll
        for (int i = 0; i < 4; i++)
#pragma unroll
            for (int j = 0; j < 4; j++)
                acc[i][j] = MF(av[i], bv[j], acc[i][j]);
        __syncthreads();
        buf ^= 1;
    }
#undef STAGE

    const int crow0 = bx * 128 + wm + lg * 4;
    const int ccol0 = by * 128 + wn + lm;
#pragma unroll
    for (int i = 0; i < 4; i++)
#pragma unroll
        for (int j = 0; j < 4; j++)
#pragma unroll
            for (int r = 0; r < 4; r++) {
                long row = crow0 + i * 16 + r;
                int  col = ccol0 + j * 16;
                float vv = acc[i][j][r];
                if (Cf) Cf[row * 1024 + col] = vv;
                else    Cb[(long)(col >> 10) * sstride + row * 1024 + (col & 1023)] = f2bf(vv);
            }
}

// ---------------------------------------------------------------- depthwise conv K=4 + silu
__global__ __launch_bounds__(256) void conv_silu_k(
    const u16* __restrict__ pre, const float* __restrict__ w,
    const float* __restrict__ bias, float* __restrict__ out)
{
    int c  = blockIdx.y * 256 + threadIdx.x;
    int bi = blockIdx.x;              // B * (T/64)
    int b  = bi >> 5;
    int t0 = (bi & 31) << 6;
    float w0 = w[c*4+0], w1 = w[c*4+1], w2 = w[c*4+2], w3 = w[c*4+3];
    float bs = bias[c];
    long base = ((long)b * Tsz) * Csz + c;
    float xm3 = (t0 >= 3) ? bf2f(pre[base + (long)(t0-3)*Csz]) : 0.f;
    float xm2 = (t0 >= 2) ? bf2f(pre[base + (long)(t0-2)*Csz]) : 0.f;
    float xm1 = (t0 >= 1) ? bf2f(pre[base + (long)(t0-1)*Csz]) : 0.f;
    for (int t = t0; t < t0 + 64; t++) {
        float xc = bf2f(pre[base + (long)t * Csz]);
        float z  = bs + w0*xm3 + w1*xm2 + w2*xm1 + w3*xc;
        out[base + (long)t * Csz] = z / (1.f + expf(-z));
        xm3 = xm2; xm2 = xm1; xm1 = xc;
    }
}

// ---------------------------------------------------------------- rope + l2norm (in-place, f32)
__global__ __launch_bounds__(256) void rope_l2norm_k(
    float* __restrict__ qk, const float* __restrict__ ctab, const float* __restrict__ stab)
{
    int row = blockIdx.x * 4 + (threadIdx.x >> 6);
    int j   = threadIdx.x & 63;
    int t   = (row >> 4) & (Tsz - 1);
    int p   = j & 31, m = j & 15, hi = j >> 5;
    float2 xv = *(const float2*)(qk + (long)row * 64 + p * 2);
    float c = ctab[t * 16 + m], s = stab[t * 16 + m];
    float val = hi ? (xv.x * s + xv.y * c) : (xv.x * c - xv.y * s);
    float ss = val * val;
#pragma unroll
    for (int off = 1; off < 64; off <<= 1) ss += __shfl_xor(ss, off);
    float inv = 1.f / fmaxf(sqrtf(ss), 1e-12f);
    qk[(long)row * 64 + j] = val * inv;
}

// ---------------------------------------------------------------- beta / log-alpha
__global__ __launch_bounds__(256) void ab_k(
    const float* __restrict__ x,
    const float* __restrict__ Wb,  const float* __restrict__ bb,
    const float* __restrict__ Wgk, const float* __restrict__ bgk,
    const float* __restrict__ A_log, const float* __restrict__ dtb,
    float* __restrict__ lalpha, float* __restrict__ beta)
{
    __shared__ float xr[1024];
    int bt = blockIdx.x;
    const float* xp = x + (long)bt * 1024;
#pragma unroll
    for (int i = 0; i < 4; i++) xr[threadIdx.x + i * 256] = xp[threadIdx.x + i * 256];
    __syncthreads();
    int wv = threadIdx.x >> 6, l = threadIdx.x & 63;
#pragma unroll
    for (int oo = 0; oo < 8; oo++) {
        int o = wv * 8 + oo;           // 0..15: beta, 16..31: lalpha
        int h = o & 15;
        const float* wr = (o < 16 ? Wb : Wgk) + (long)h * 1024;
        float p = 0.f;
#pragma unroll
        for (int i = 0; i < 16; i++) p += wr[l + i * 64] * xr[l + i * 64];
        for (int off = 32; off; off >>= 1) p += __shfl_xor(p, off);
        if (l == 0) {
            if (o < 16) {
                beta[bt * 16 + h] = 1.f / (1.f + expf(-(p + bb[h])));
            } else {
                float gk = p + bgk[h] + dtb[h];
                float sp = gk > 0.f ? gk + log1pf(expf(-gk)) : log1pf(expf(gk));
                lalpha[bt * 16 + h] = -expf(A_log[h]) * sp;   // log(alpha)
            }
        }
    }
}

// ---------------------------------------------------------------- Phase A: per-chunk WY precompute
__global__ __launch_bounds__(256) void chunk_prep_k(
    const float* __restrict__ q, const float* __restrict__ k, const float* __restrict__ v,
    const float* __restrict__ lalpha, const float* __restrict__ beta,
    u16* __restrict__ Wg_, u16* __restrict__ Amat_, u16* __restrict__ Qg_,
    u16* __restrict__ KpT_, float* __restrict__ U_, float* __restrict__ gend_)
{
    __shared__ u16   Kb[64][72];
    __shared__ u16   Qb[64][72];
    __shared__ float Lm[64][68];
    __shared__ float WU[64][132];
    __shared__ float lgS[64];
    __shared__ float betaS[64];

    const int tile = blockIdx.x;
    const int bh = tile >> 5, n = tile & 31;
    const int b = bh >> 4, h = bh & 15;
    const int t0 = n << 6;
    const int tid = threadIdx.x;
    const int lane = tid & 63, wv = tid >> 6;
    const int lm = lane & 15, lg = lane >> 4;

    // log-gamma inclusive scan + beta staging (wave 0)
    if (wv == 0) {
        long rix = ((long)(b * Tsz + t0 + lane)) * Hsz + h;
        float lgv = lalpha[rix];
#pragma unroll
        for (int off = 1; off < 64; off <<= 1) {
            float u = __shfl_up(lgv, off);
            if (lane >= off) lgv += u;
        }
        lgS[lane] = lgv;
        betaS[lane] = beta[rix];
    }
    // load K,Q tiles -> bf16 LDS
    {
        int row = tid >> 2, c0 = (tid & 3) << 4;
        long gb = ((long)(b * Tsz + t0 + row) * Hsz + h) << 6;
#pragma unroll
        for (int j = 0; j < 4; j++) {
            float4 kk = *(const float4*)(k + gb + c0 + 4*j);
            float4 qq = *(const float4*)(q + gb + c0 + 4*j);
            us4 kw, qw;
            kw.x=f2bf(kk.x); kw.y=f2bf(kk.y); kw.z=f2bf(kk.z); kw.w=f2bf(kk.w);
            qw.x=f2bf(qq.x); qw.y=f2bf(qq.y); qw.z=f2bf(qq.z); qw.w=f2bf(qq.w);
            *(us4*)&Kb[row][c0 + 4*j] = kw;
            *(us4*)&Qb[row][c0 + 4*j] = qw;
        }
    }
    __syncthreads();

    // Mkk, Mqk via MFMA; scaled L (f32 LDS) and Amat (bf16 global)
    {
        const int ar = 16*wv + lm;
        bf16x8_t Ka0 = *(const bf16x8_t*)&Kb[ar][8*lg];
        bf16x8_t Ka1 = *(const bf16x8_t*)&Kb[ar][32 + 8*lg];
        bf16x8_t Qa0 = *(const bf16x8_t*)&Qb[ar][8*lg];
        bf16x8_t Qa1 = *(const bf16x8_t*)&Qb[ar][32 + 8*lg];
        f32x4 aKK[4], aQK[4];
#pragma unroll
        for (int nt=0; nt<4; nt++){ aKK[nt]=(f32x4){0,0,0,0}; aQK[nt]=(f32x4){0,0,0,0}; }
#pragma unroll
        for (int nt=0; nt<4; nt++){
            int br = 16*nt + lm;
            bf16x8_t B0 = *(const bf16x8_t*)&Kb[br][8*lg];
            bf16x8_t B1 = *(const bf16x8_t*)&Kb[br][32 + 8*lg];
            aKK[nt] = MF(Ka0, B0, aKK[nt]); aKK[nt] = MF(Ka1, B1, aKK[nt]);
            aQK[nt] = MF(Qa0, B0, aQK[nt]); aQK[nt] = MF(Qa1, B1, aQK[nt]);
        }
#pragma unroll
        for (int r=0; r<4; r++){
            int t = 16*wv + 4*lg + r;
            float lgt = lgS[t];
            float bt = betaS[t];
#pragma unroll
            for (int nt=0; nt<4; nt++){
                int s = 16*nt + lm;
                float ratio = expf(lgt - lgS[s]);
                Lm[t][s] = (s < t) ? bt * ratio * aKK[nt][r] : 0.f;
                Amat_[(long)tile*4096 + t*64 + s] = f2bf((s <= t) ? ratio * aQK[nt][r] : 0.f);
            }
        }
    }
    // init WU = [diag(b*gamma)K | diag(b)V]  (f32, from global)
    {
        int row = tid >> 2, qd = tid & 3;
        long gb = ((long)(b * Tsz + t0 + row) * Hsz + h) << 6;
        float bt = betaS[row];
        float gt = expf(lgS[row]);
        if (qd < 2) {
            int c0 = qd * 32;
            float bg = bt * gt;
#pragma unroll
            for (int j = 0; j < 8; j++) {
                float4 kk = *(const float4*)(k + gb + c0 + 4*j);
                WU[row][c0+4*j+0] = bg*kk.x; WU[row][c0+4*j+1] = bg*kk.y;
                WU[row][c0+4*j+2] = bg*kk.z; WU[row][c0+4*j+3] = bg*kk.w;
            }
        } else {
            int c0 = (qd - 2) * 32;
#pragma unroll
            for (int j = 0; j < 8; j++) {
                float4 vv = *(const float4*)(v + gb + c0 + 4*j);
                WU[row][64+c0+4*j+0] = bt*vv.x; WU[row][64+c0+4*j+1] = bt*vv.y;
                WU[row][64+c0+4*j+2] = bt*vv.z; WU[row][64+c0+4*j+3] = bt*vv.w;
            }
        }
    }
    __syncthreads();

    // forward substitution: (I+L) X = rhs, column-owned, X in registers.
    if (tid < 128) {
        float X[64];
        X[0] = WU[0][tid];
#pragma unroll
        for (int r = 1; r < 64; r++) {
            float a0 = 0.f, a1 = 0.f, a2 = 0.f, a3 = 0.f;
            const float4* L4 = (const float4*)&Lm[r][0];
#pragma unroll
            for (int j = 0; 4*j < r; j++) {
                float4 lv = L4[j];                // wave-uniform broadcast read
                int s = 4*j;
                a0 += lv.x * X[s];
                if (s+1 < r) a1 += lv.y * X[s+1];
                if (s+2 < r) a2 += lv.z * X[s+2];
                if (s+3 < r) a3 += lv.w * X[s+3];
            }
            X[r] = WU[r][tid] - ((a0+a1)+(a2+a3));
        }
#pragma unroll
        for (int r = 0; r < 64; r++) WU[r][tid] = X[r];
    }
    __syncthreads();

    // outputs
    {
        int row = tid >> 2, c0 = (tid & 3) << 4;
        float gt  = expf(lgS[row]);
        float lge = lgS[63];
        long tb = (long)tile * 4096;
#pragma unroll
        for (int c = c0; c < c0 + 16; c++) {
            Wg_[tb + row*64 + c] = f2bf(WU[row][c]);
            U_ [tb + row*64 + c] = WU[row][64 + c];
            Qg_[tb + row*64 + c] = f2bf(gt * bf2f(Qb[row][c]));
            KpT_[tb + row*64 + c] = f2bf(expf(lge - lgS[c]) * bf2f(Kb[c][row]));
        }
        if (tid == 0) gend_[tile] = expf(lge);
    }
}

// ---------------------------------------------------------------- Phase B: sequential chunk scan
// dv-parallel: 128 blocks = 4 dv-slices x 32 (b,h); 1 wave each.
// bid = slice*32 + bh  (stride 32 == 0 mod 8 -> all 4 slices of a bh share an XCD/L2).
// S slice [16 dv][64 dk] lives in registers (acc layout); LDS only for the
// two transposes (S acc->B-layout, C->CT). Barriers are 1-wave (cheap).
__global__ __launch_bounds__(64) void chunk_scan_k(
    const u16* __restrict__ Wg_, const u16* __restrict__ Amat_, const u16* __restrict__ Qg_,
    const u16* __restrict__ KpT_, const float* __restrict__ U_, const float* __restrict__ gend_,
    u16* __restrict__ oact)
{
    __shared__ float Sl[16][68];
    __shared__ u16   CT[16][72];
    const int bid = blockIdx.x;
    const int sl = bid >> 5, bh = bid & 31;
    const int b = bh >> 4, h = bh & 15;
    const int dv0 = sl << 4;
    const int lane = threadIdx.x;
    const int lm = lane & 15, lg = lane >> 4;

    f32x4 Sacc0 = {0,0,0,0}, Sacc1 = {0,0,0,0}, Sacc2 = {0,0,0,0}, Sacc3 = {0,0,0,0};

    for (int n = 0; n < 32; n++) {
        const long tb = ((long)(bh*32 + n)) << 12;
        // ---- S (acc layout regs) -> Sl[dv][dk]
#pragma unroll
        for (int r = 0; r < 4; r++) {
            Sl[4*lg + r][ 0 + lm] = Sacc0[r];
            Sl[4*lg + r][16 + lm] = Sacc1[r];
            Sl[4*lg + r][32 + lm] = Sacc2[r];
            Sl[4*lg + r][48 + lm] = Sacc3[r];
        }
        // ---- issue W, Q, U loads (needed pre-sync2)
        bf16x8_t Wa[4][2], Qa[4][2];
#pragma unroll
        for (int ti = 0; ti < 4; ti++)
#pragma unroll
            for (int kh = 0; kh < 2; kh++) {
                Wa[ti][kh] = *(const bf16x8_t*)(Wg_ + tb + (16*ti + lm)*64 + 32*kh + 8*lg);
                Qa[ti][kh] = *(const bf16x8_t*)(Qg_ + tb + (16*ti + lm)*64 + 32*kh + 8*lg);
            }
        float Uv[4][4];
#pragma unroll
        for (int ti = 0; ti < 4; ti++)
#pragma unroll
            for (int r = 0; r < 4; r++)
                Uv[ti][r] = U_[tb + (16*ti + 4*lg + r)*64 + dv0 + lm];
        const float ge = gend_[bh*32 + n];
        __syncthreads();
        // ---- S B-layout frags + hi/lo split
        bf16x8_t Shi[2], Slo[2];
#pragma unroll
        for (int kh = 0; kh < 2; kh++) {
            const float* sp = &Sl[lm][32*kh + 8*lg];
            float4 aa = *(const float4*)sp;
            float4 bb = *(const float4*)(sp + 4);
            float xs[8] = {aa.x,aa.y,aa.z,aa.w,bb.x,bb.y,bb.z,bb.w};
#pragma unroll
            for (int j = 0; j < 8; j++) {
                u16 hv = f2bf(xs[j]);
                Shi[kh][j] = (short)hv;
                Slo[kh][j] = (short)f2bf(xs[j] - bf2f(hv));
            }
        }
        // ---- P = W * S^T (hi+lo);  C = U - P -> CT[v][t]
        f32x4 accP[4];
#pragma unroll
        for (int ti = 0; ti < 4; ti++) {
            accP[ti] = (f32x4){0,0,0,0};
            accP[ti] = MF(Wa[ti][0], Shi[0], accP[ti]);
            accP[ti] = MF(Wa[ti][0], Slo[0], accP[ti]);
            accP[ti] = MF(Wa[ti][1], Shi[1], accP[ti]);
            accP[ti] = MF(Wa[ti][1], Slo[1], accP[ti]);
        }
#pragma unroll
        for (int ti = 0; ti < 4; ti++)
#pragma unroll
            for (int r = 0; r < 4; r++)
                CT[lm][16*ti + 4*lg + r] = f2bf(Uv[ti][r] - accP[ti][r]);
        // ---- issue A, Kp loads (needed post-sync2)
        bf16x8_t Aa[4][2], Kp[4][2];
#pragma unroll
        for (int ti = 0; ti < 4; ti++)
#pragma unroll
            for (int sh = 0; sh < 2; sh++) {
                Aa[ti][sh] = *(const bf16x8_t*)(Amat_ + tb + (16*ti + lm)*64 + 32*sh + 8*lg);
                Kp[ti][sh] = *(const bf16x8_t*)(KpT_  + tb + (16*ti + lm)*64 + 32*sh + 8*lg);
            }
        // ---- O1 = gam*Q * S^T (hi+lo)
        f32x4 accO[4];
#pragma unroll
        for (int ti = 0; ti < 4; ti++) {
            accO[ti] = (f32x4){0,0,0,0};
            accO[ti] = MF(Qa[ti][0], Shi[0], accO[ti]);
            accO[ti] = MF(Qa[ti][0], Slo[0], accO[ti]);
            accO[ti] = MF(Qa[ti][1], Shi[1], accO[ti]);
            accO[ti] = MF(Qa[ti][1], Slo[1], accO[ti]);
        }
        __syncthreads();
        // ---- CT frags (A for S', B for O2)
        bf16x8_t CTf[2];
        CTf[0] = *(const bf16x8_t*)&CT[lm][8*lg];
        CTf[1] = *(const bf16x8_t*)&CT[lm][32 + 8*lg];
        // ---- O2 = Amat * C^T
#pragma unroll
        for (int ti = 0; ti < 4; ti++) {
            accO[ti] = MF(Aa[ti][0], CTf[0], accO[ti]);
            accO[ti] = MF(Aa[ti][1], CTf[1], accO[ti]);
        }
        // ---- S' = gend*S + Kp^T C
        f32x4 accS0, accS1, accS2, accS3;
        accS0 = (f32x4){ge*Sacc0[0], ge*Sacc0[1], ge*Sacc0[2], ge*Sacc0[3]};
        accS1 = (f32x4){ge*Sacc1[0], ge*Sacc1[1], ge*Sacc1[2], ge*Sacc1[3]};
        accS2 = (f32x4){ge*Sacc2[0], ge*Sacc2[1], ge*Sacc2[2], ge*Sacc2[3]};
        accS3 = (f32x4){ge*Sacc3[0], ge*Sacc3[1], ge*Sacc3[2], ge*Sacc3[3]};
        accS0 = MF(CTf[0], Kp[0][0], accS0); accS0 = MF(CTf[1], Kp[0][1], accS0);
        accS1 = MF(CTf[0], Kp[1][0], accS1); accS1 = MF(CTf[1], Kp[1][1], accS1);
        accS2 = MF(CTf[0], Kp[2][0], accS2); accS2 = MF(CTf[1], Kp[2][1], accS2);
        accS3 = MF(CTf[0], Kp[3][0], accS3); accS3 = MF(CTf[1], Kp[3][1], accS3);
        Sacc0 = accS0; Sacc1 = accS1; Sacc2 = accS2; Sacc3 = accS3;
        // ---- write O slice
        const int trow = n*64 + 4*lg;
#pragma unroll
        for (int ti = 0; ti < 4; ti++)
#pragma unroll
            for (int r = 0; r < 4; r++)
                oact[(long)(b*Tsz + trow + 16*ti + r)*1024 + h*64 + dv0 + lm] = f2bf(accO[ti][r]);
        __syncthreads();   // CT reads / Sl reads complete before next chunk's writes
    }
}

// ---------------------------------------------------------------- epilogue: +Dp*v, rmsnorm, silu, gate
__global__ __launch_bounds__(256) void epi2_k(
    u16* __restrict__ o, const u16* __restrict__ g, const float* __restrict__ vc,
    const float* __restrict__ Dp, const float* __restrict__ onw)
{
    long row = (long)blockIdx.x * 4 + (threadIdx.x >> 6);
    int lane = threadIdx.x & 63;
    int h = (int)(row & 15);
    long idx = (row << 6) + lane;
    float ov = bf2f(o[idx]) + Dp[h] * vc[idx];
    float gv = bf2f(g[idx]);
    float ss = ov * ov;
#pragma unroll
    for (int off = 1; off < 64; off <<= 1) ss += __shfl_xor(ss, off);
    float r   = rsqrtf(ss * (1.f / 64.f) + 1e-6f);
    float on  = onw[lane] * (ov * r);
    float sil = on / (1.f + expf(-on));
    o[idx] = f2bf(gv * sil);
}

// ---------------------------------------------------------------- host launch
extern "C" void kernel_launch(void* const* d_in, const int* in_sizes, int n_in,
                              void* d_out, int out_size, void* d_ws, size_t ws_size,
                              hipStream_t stream)
{
    const float* x    = (const float*)d_in[0];
    const float* Wq   = (const float*)d_in[1];
    const float* Wk   = (const float*)d_in[2];
    const float* Wv   = (const float*)d_in[3];
    const float* Wg   = (const float*)d_in[4];
    const float* Wo   = (const float*)d_in[5];
    const float* Wb   = (const float*)d_in[6];
    const float* bb   = (const float*)d_in[7];
    const float* Wgk  = (const float*)d_in[8];
    const float* bgk  = (const float*)d_in[9];
    const float* cqw  = (const float*)d_in[10];
    const float* cqb  = (const float*)d_in[11];
    const float* ckw  = (const float*)d_in[12];
    const float* ckb  = (const float*)d_in[13];
    const float* cvw  = (const float*)d_in[14];
    const float* cvb  = (const float*)d_in[15];
    const float* A_log= (const float*)d_in[16];
    const float* Dp   = (const float*)d_in[17];
    const float* dtb  = (const float*)d_in[18];
    const float* onw  = (const float*)d_in[19];
    float* out = (float*)d_out;

    char* p = (char*)d_ws;
    auto alloc = [&](size_t bytes) -> char* {
        char* r = p; p += (bytes + 255) & ~(size_t)255; return r;
    };
    const size_t NBT = (size_t)BT * Csz;          // 4M elements
    const size_t NTILE = (size_t)32 * 32;         // 1024 chunk tiles
    u16*   xbf   = (u16*)  alloc(NBT * 2);
    u16*   wcat  = (u16*)  alloc((size_t)4 * Csz * Csz * 2);  // [Wq;Wk;Wv;Wg] bf16, contiguous
    u16*   Wobf  = (u16*)  alloc((size_t)Csz * Csz * 2);
    u16*   qkvg  = (u16*)  alloc((size_t)4 * NBT * 2);        // qpre|kpre|vpre|gbf contiguous
    float* qconv = (float*)alloc(NBT * 4);
    float* kconv = (float*)alloc(NBT * 4);
    float* ctab  = (float*)alloc((size_t)Tsz * 16 * 4);
    float* stab  = (float*)alloc((size_t)Tsz * 16 * 4);
    float* lalpha= (float*)alloc((size_t)BT * Hsz * 4);
    float* beta  = (float*)alloc((size_t)BT * Hsz * 4);
    u16*   Wg_t  = (u16*)  alloc(NTILE * 4096 * 2);
    u16*   Amat_t= (u16*)  alloc(NTILE * 4096 * 2);
    u16*   Qg_t  = (u16*)  alloc(NTILE * 4096 * 2);
    u16*   KpT_t = (u16*)  alloc(NTILE * 4096 * 2);
    float* U_t   = (float*)alloc(NTILE * 4096 * 4);
    float* gend_t= (float*)alloc(NTILE * 4);

    u16* Wqbf = wcat;
    u16* Wkbf = wcat + (size_t)Csz * Csz;
    u16* Wvbf = wcat + (size_t)2 * Csz * Csz;
    u16* Wgbf = wcat + (size_t)3 * Csz * Csz;
    u16* qpre = qkvg;
    u16* vpre = qkvg + 2 * NBT;
    u16* gbf  = qkvg + 3 * NBT;
    // overlays (stream-ordered reuse of dead buffers):
    float* vconv = (float*)qpre;   // 16MB over qpre+kpre (dead after conv_q/conv_k)
    u16*   oact  = (u16*)vpre;     // 8MB over vpre (dead after conv_v)

    // 1. rope tables
    rope_tables_k<<<(Tsz * 16 + 255) / 256, 256, 0, stream>>>(ctab, stab);

    // 2. f32 -> bf16 conversions
    cvt_f32_bf16_k<<<(int)(NBT / 4 + 255) / 256, 256, 0, stream>>>(x,  xbf,  (int)NBT);
    cvt_f32_bf16_k<<<(Csz * Csz / 4 + 255) / 256, 256, 0, stream>>>(Wq, Wqbf, Csz * Csz);
    cvt_f32_bf16_k<<<(Csz * Csz / 4 + 255) / 256, 256, 0, stream>>>(Wk, Wkbf, Csz * Csz);
    cvt_f32_bf16_k<<<(Csz * Csz / 4 + 255) / 256, 256, 0, stream>>>(Wv, Wvbf, Csz * Csz);
    cvt_f32_bf16_k<<<(Csz * Csz / 4 + 255) / 256, 256, 0, stream>>>(Wg, Wgbf, Csz * Csz);
    cvt_f32_bf16_k<<<(Csz * Csz / 4 + 255) / 256, 256, 0, stream>>>(Wo, Wobf, Csz * Csz);

    // 3. fused QKVG projection: M=4096, N=4096 over contiguous weights, split-store
    gemm_bf16_nt<<<32 * 32, 256, 0, stream>>>(xbf, wcat, nullptr, qkvg, 32, (long)NBT, Csz);

    // 4. depthwise conv + silu (f32 out)
    dim3 cgrid(Bsz * (Tsz / 64), Csz / 256);
    conv_silu_k<<<cgrid, 256, 0, stream>>>(qpre,            cqw, cqb, qconv);
    conv_silu_k<<<cgrid, 256, 0, stream>>>(qkvg + NBT,      ckw, ckb, kconv);
    conv_silu_k<<<cgrid, 256, 0, stream>>>(vpre,            cvw, cvb, vconv);

    // 5. rope + l2norm, in place on q/k
    rope_l2norm_k<<<(Bsz * Tsz * Hsz) / 4, 256, 0, stream>>>(qconv, ctab, stab);
    rope_l2norm_k<<<(Bsz * Tsz * Hsz) / 4, 256, 0, stream>>>(kconv, ctab, stab);

    // 6. beta / log-alpha
    ab_k<<<BT, 256, 0, stream>>>(x, Wb, bb, Wgk, bgk, A_log, dtb, lalpha, beta);

    // 7a. chunk precompute (parallel over 1024 tiles)
    chunk_prep_k<<<1024, 256, 0, stream>>>(qconv, kconv, vconv, lalpha, beta,
                                           Wg_t, Amat_t, Qg_t, KpT_t, U_t, gend_t);

    // 7b. sequential chunk scan: 4 dv-slices x 32 (b,h), 1 wave each
    chunk_scan_k<<<128, 64, 0, stream>>>(Wg_t, Amat_t, Qg_t, KpT_t, U_t, gend_t, oact);

    // 8. epilogue: D-skip + rmsnorm + silu + gate, in place on oact
    epi2_k<<<(BT * Hsz) / 4, 256, 0, stream>>>(oact, gbf, vconv, Dp, onw);

    // 9. output projection (f32 -> d_out)
    gemm_bf16_nt<<<32 * 8, 256, 0, stream>>>(oact, Wobf, out, nullptr, 32, 0L, Csz);

    (void)in_sizes; (void)n_in; (void)out_size; (void)ws_size;
}

// Round 10
// 405.909 us; speedup vs baseline: 16.1628x; 1.0251x over previous
//
#include <hip/hip_runtime.h>

#define Bsz 2
#define Tsz 2048
#define Csz 1024
#define Hsz 16
#define Dsz 64
#define BT (Bsz*Tsz)   // 4096

typedef unsigned short u16;
typedef __attribute__((ext_vector_type(8))) short bf16x8_t;
typedef __attribute__((ext_vector_type(4))) float f32x4;
typedef __attribute__((ext_vector_type(4))) unsigned short us4;

#define MF(a,b,c) __builtin_amdgcn_mfma_f32_16x16x32_bf16(a,b,c,0,0,0)

__device__ __forceinline__ float bf2f(u16 u){
    union { unsigned i; float f; } c; c.i = ((unsigned)u) << 16; return c.f;
}
__device__ __forceinline__ u16 f2bf(float f){
    union { float f; unsigned i; } c; c.f = f;
    unsigned i = c.i;
    unsigned r = (i + 0x7fffu + ((i >> 16) & 1u)) >> 16;
    return (u16)r;
}
__device__ __forceinline__ void gload_lds16(const void* g, void* l){
    __builtin_amdgcn_global_load_lds(
        (const __attribute__((address_space(1))) unsigned int*)g,
        (__attribute__((address_space(3))) unsigned int*)l, 16, 0, 0);
}

// ---------------------------------------------------------------- rope tables
__global__ void rope_tables_k(float* __restrict__ ctab, float* __restrict__ stab){
    int idx = blockIdx.x * blockDim.x + threadIdx.x;
    if (idx >= Tsz * 16) return;
    int t = idx >> 4, m = idx & 15;
    float arf = (float)m / 16.f;                   // ar[i]=i/32, i=2m
    double sb = 10000.0 * pow(32.0, 64.0 / 62.0);  // scaled_base
    float invf = (float)(1.0 / pow(sb, (double)arf));
    float fe   = (float)(1.0 / pow(10000.0, (double)arf));
    float wl   = 6.283185307179586f / fe;
    float ms   = fminf(fmaxf((wl - 1.0f) / 31.0f, 0.f), 1.f);
    float scale = 1.f + 31.f * ms;
    float freq = ((float)t / scale) * invf;
    ctab[idx] = cosf(freq);
    stab[idx] = sinf(freq);
}

// ---------------------------------------------------------------- f32 -> bf16 (x)
__global__ void cvt_f32_bf16_k(const float* __restrict__ in, u16* __restrict__ out, int n){
    int i = (blockIdx.x * blockDim.x + threadIdx.x) * 4;
    if (i >= n) return;
    float4 v = *(const float4*)(in + i);
    us4 o; o.x = f2bf(v.x); o.y = f2bf(v.y); o.z = f2bf(v.z); o.w = f2bf(v.w);
    *(us4*)(out + i) = o;
}

// ---------------------------------------------------------------- f32 -> bf16 (5 weight mats, fused)
__global__ void cvt_w_k(const float* __restrict__ s0, const float* __restrict__ s1,
                        const float* __restrict__ s2, const float* __restrict__ s3,
                        const float* __restrict__ s4, u16* __restrict__ dst){
    int y = blockIdx.y;
    const float* s = (y == 0) ? s0 : (y == 1) ? s1 : (y == 2) ? s2 : (y == 3) ? s3 : s4;
    int i = (blockIdx.x * blockDim.x + threadIdx.x) * 4;
    float4 v = *(const float4*)(s + i);
    us4 o; o.x = f2bf(v.x); o.y = f2bf(v.y); o.z = f2bf(v.z); o.w = f2bf(v.w);
    *(us4*)(dst + (size_t)y * Csz * Csz + i) = o;
}

// ---------------------------------------------------------------- bf16 MFMA GEMM (LDS-staged + T2 XOR swizzle)
// C = A * Bw^T. LDS dest stays LINEAR (global_load_lds reqmt, rule #21);
// bank-spread via pre-swizzled SOURCE chunk + swizzled ds_read chunk:
//   slot (row, cs) holds global chunk cs ^ ((row>>1)&3).
__global__ __launch_bounds__(256) void gemm_bf16_nt(
    const u16* __restrict__ A, const u16* __restrict__ Bw,
    float* __restrict__ Cf, u16* __restrict__ Cb,
    int gm, long sstride, int Kdim)
{
    __shared__ u16 As[2][128*32];
    __shared__ u16 Bs[2][128*32];

    const int nwg = gridDim.x;
    const int q8  = nwg >> 3;
    const int id  = blockIdx.x;
    const int swz = (id & 7) * q8 + (id >> 3);
    const int bx  = swz % gm;
    const int by  = swz / gm;

    const int tid = threadIdx.x;
    const int w  = tid >> 6, l = tid & 63;
    const int lm = l & 15,  lg = l >> 4;
    const int wm = (w >> 1) << 6;
    const int wn = (w & 1) << 6;

    // staging: wave w stages 16-row chunks {w, w+4}; LDS byte = w*1024 + l*16 (linear).
    const int r0  = (w << 4) + (l >> 2);                 // rows 0..63
    const int kof = (((l & 3) ^ ((l >> 3) & 3)) << 3);   // SWIZZLED source chunk (elements)
    const long ga0 = (long)(bx * 128 + r0)      * Kdim + kof;
    const long ga1 = (long)(bx * 128 + r0 + 64) * Kdim + kof;
    const long gb0 = (long)(by * 128 + r0)      * Kdim + kof;
    const long gb1 = (long)(by * 128 + r0 + 64) * Kdim + kof;
    const int  ldst = r0 * 32 + ((l & 3) << 3);          // LINEAR LDS dest (elements)

    f32x4 acc[4][4];
#pragma unroll
    for (int i = 0; i < 4; i++)
#pragma unroll
        for (int j = 0; j < 4; j++) acc[i][j] = (f32x4){0.f, 0.f, 0.f, 0.f};

    const int nt = Kdim >> 5;
#define STAGE(B_, T_) do { int k0_ = (T_) << 5;                       \
        gload_lds16(A  + ga0 + k0_, &As[B_][ldst]);                   \
        gload_lds16(A  + ga1 + k0_, &As[B_][ldst + 2048]);            \
        gload_lds16(Bw + gb0 + k0_, &Bs[B_][ldst]);                   \
        gload_lds16(Bw + gb1 + k0_, &Bs[B_][ldst + 2048]);            \
    } while (0)

    STAGE(0, 0);
    __syncthreads();
    int buf = 0;
    const int csw = (lg ^ ((lm >> 1) & 3)) << 3;         // swizzled read chunk (elements)
    for (int t = 0; t < nt; t++) {
        if (t + 1 < nt) STAGE(buf ^ 1, t + 1);
        bf16x8_t av[4], bv[4];
#pragma unroll
        for (int i = 0; i < 4; i++) av[i] = *(const bf16x8_t*)&As[buf][(wm + i*16 + lm)*32 + csw];
#pragma unroll
        for (int j = 0; j < 4; j++) bv[j] = *(const bf16x8_t*)&Bs[buf][(wn + j*16 + lm)*32 + csw];
#pragma unroll
        for (int i = 0; i < 4; i++)
#pragma unroll
            for (int j = 0; j < 4; j++)
                acc[i][j] = MF(av[i], bv[j], acc[i][j]);
        __syncthreads();
        buf ^= 1;
    }
#undef STAGE

    const int crow0 = bx * 128 + wm + lg * 4;
    const int ccol0 = by * 128 + wn + lm;
#pragma unroll
    for (int i = 0; i < 4; i++)
#pragma unroll
        for (int j = 0; j < 4; j++)
#pragma unroll
            for (int r = 0; r < 4; r++) {
                long row = crow0 + i * 16 + r;
                int  col = ccol0 + j * 16;
                float vv = acc[i][j][r];
                if (Cf) Cf[row * 1024 + col] = vv;
                else    Cb[(long)(col >> 10) * sstride + row * 1024 + (col & 1023)] = f2bf(vv);
            }
}

// ---------------------------------------------------------------- depthwise conv K=4 + silu
// z = blockIdx.z + zbase selects tensor (0:q 1:k 2:v). v MUST run in a separate
// launch AFTER q/k (vconv overlays qpre/kpre — stream-order dependency).
__global__ __launch_bounds__(256) void conv_silu_k(
    const u16* __restrict__ qkvg, int zbase,
    const float* __restrict__ cqw, const float* __restrict__ cqb,
    const float* __restrict__ ckw, const float* __restrict__ ckb,
    const float* __restrict__ cvw, const float* __restrict__ cvb,
    float* __restrict__ qc, float* __restrict__ kc, float* __restrict__ vc)
{
    int z = blockIdx.z + zbase;
    const u16* pre = qkvg + (size_t)z * BT * Csz;
    const float* w  = (z == 0) ? cqw : (z == 1) ? ckw : cvw;
    const float* bv = (z == 0) ? cqb : (z == 1) ? ckb : cvb;
    float* out = (z == 0) ? qc : (z == 1) ? kc : vc;

    int c  = blockIdx.y * 256 + threadIdx.x;
    int bi = blockIdx.x;              // B * (T/64)
    int b  = bi >> 5;
    int t0 = (bi & 31) << 6;
    float w0 = w[c*4+0], w1 = w[c*4+1], w2 = w[c*4+2], w3 = w[c*4+3];
    float bs = bv[c];
    long base = ((long)b * Tsz) * Csz + c;
    float xm3 = (t0 >= 3) ? bf2f(pre[base + (long)(t0-3)*Csz]) : 0.f;
    float xm2 = (t0 >= 2) ? bf2f(pre[base + (long)(t0-2)*Csz]) : 0.f;
    float xm1 = (t0 >= 1) ? bf2f(pre[base + (long)(t0-1)*Csz]) : 0.f;
    for (int t = t0; t < t0 + 64; t++) {
        float xc = bf2f(pre[base + (long)t * Csz]);
        float z2 = bs + w0*xm3 + w1*xm2 + w2*xm1 + w3*xc;
        out[base + (long)t * Csz] = z2 / (1.f + expf(-z2));
        xm3 = xm2; xm2 = xm1; xm1 = xc;
    }
}

// ---------------------------------------------------------------- rope + l2norm (q and k fused, in-place, f32)
__global__ __launch_bounds__(256) void rope_l2norm_k(
    float* __restrict__ q, float* __restrict__ k,
    const float* __restrict__ ctab, const float* __restrict__ stab)
{
    float* qk = blockIdx.y ? k : q;
    int row = blockIdx.x * 4 + (threadIdx.x >> 6);
    int j   = threadIdx.x & 63;
    int t   = (row >> 4) & (Tsz - 1);
    int p   = j & 31, m = j & 15, hi = j >> 5;
    float2 xv = *(const float2*)(qk + (long)row * 64 + p * 2);
    float c = ctab[t * 16 + m], s = stab[t * 16 + m];
    float val = hi ? (xv.x * s + xv.y * c) : (xv.x * c - xv.y * s);
    float ss = val * val;
#pragma unroll
    for (int off = 1; off < 64; off <<= 1) ss += __shfl_xor(ss, off);
    float inv = 1.f / fmaxf(sqrtf(ss), 1e-12f);
    qk[(long)row * 64 + j] = val * inv;
}

// ---------------------------------------------------------------- beta / log-alpha
__global__ __launch_bounds__(256) void ab_k(
    const float* __restrict__ x,
    const float* __restrict__ Wb,  const float* __restrict__ bb,
    const float* __restrict__ Wgk, const float* __restrict__ bgk,
    const float* __restrict__ A_log, const float* __restrict__ dtb,
    float* __restrict__ lalpha, float* __restrict__ beta)
{
    __shared__ float xr[1024];
    int bt = blockIdx.x;
    const float* xp = x + (long)bt * 1024;
#pragma unroll
    for (int i = 0; i < 4; i++) xr[threadIdx.x + i * 256] = xp[threadIdx.x + i * 256];
    __syncthreads();
    int wv = threadIdx.x >> 6, l = threadIdx.x & 63;
#pragma unroll
    for (int oo = 0; oo < 8; oo++) {
        int o = wv * 8 + oo;           // 0..15: beta, 16..31: lalpha
        int h = o & 15;
        const float* wr = (o < 16 ? Wb : Wgk) + (long)h * 1024;
        float p = 0.f;
#pragma unroll
        for (int i = 0; i < 16; i++) p += wr[l + i * 64] * xr[l + i * 64];
        for (int off = 32; off; off >>= 1) p += __shfl_xor(p, off);
        if (l == 0) {
            if (o < 16) {
                beta[bt * 16 + h] = 1.f / (1.f + expf(-(p + bb[h])));
            } else {
                float gk = p + bgk[h] + dtb[h];
                float sp = gk > 0.f ? gk + log1pf(expf(-gk)) : log1pf(expf(gk));
                lalpha[bt * 16 + h] = -expf(A_log[h]) * sp;   // log(alpha)
            }
        }
    }
}

// ---------------------------------------------------------------- Phase A: per-chunk WY precompute
__global__ __launch_bounds__(256) void chunk_prep_k(
    const float* __restrict__ q, const float* __restrict__ k, const float* __restrict__ v,
    const float* __restrict__ lalpha, const float* __restrict__ beta,
    u16* __restrict__ Wg_, u16* __restrict__ Amat_, u16* __restrict__ Qg_,
    u16* __restrict__ KpT_, float* __restrict__ U_, float* __restrict__ gend_)
{
    __shared__ u16   Kb[64][72];
    __shared__ u16   Qb[64][72];
    __shared__ float Lm[64][68];
    __shared__ float WU[64][132];
    __shared__ float lgS[64];
    __shared__ float betaS[64];

    const int tile = blockIdx.x;
    const int bh = tile >> 5, n = tile & 31;
    const int b = bh >> 4, h = bh & 15;
    const int t0 = n << 6;
    const int tid = threadIdx.x;
    const int lane = tid & 63, wv = tid >> 6;
    const int lm = lane & 15, lg = lane >> 4;

    // log-gamma inclusive scan + beta staging (wave 0)
    if (wv == 0) {
        long rix = ((long)(b * Tsz + t0 + lane)) * Hsz + h;
        float lgv = lalpha[rix];
#pragma unroll
        for (int off = 1; off < 64; off <<= 1) {
            float u = __shfl_up(lgv, off);
            if (lane >= off) lgv += u;
        }
        lgS[lane] = lgv;
        betaS[lane] = beta[rix];
    }
    // load K,Q tiles -> bf16 LDS
    {
        int row = tid >> 2, c0 = (tid & 3) << 4;
        long gb = ((long)(b * Tsz + t0 + row) * Hsz + h) << 6;
#pragma unroll
        for (int j = 0; j < 4; j++) {
            float4 kk = *(const float4*)(k + gb + c0 + 4*j);
            float4 qq = *(const float4*)(q + gb + c0 + 4*j);
            us4 kw, qw;
            kw.x=f2bf(kk.x); kw.y=f2bf(kk.y); kw.z=f2bf(kk.z); kw.w=f2bf(kk.w);
            qw.x=f2bf(qq.x); qw.y=f2bf(qq.y); qw.z=f2bf(qq.z); qw.w=f2bf(qq.w);
            *(us4*)&Kb[row][c0 + 4*j] = kw;
            *(us4*)&Qb[row][c0 + 4*j] = qw;
        }
    }
    __syncthreads();

    // Mkk, Mqk via MFMA; scaled L (f32 LDS) and Amat (bf16 global)
    {
        const int ar = 16*wv + lm;
        bf16x8_t Ka0 = *(const bf16x8_t*)&Kb[ar][8*lg];
        bf16x8_t Ka1 = *(const bf16x8_t*)&Kb[ar][32 + 8*lg];
        bf16x8_t Qa0 = *(const bf16x8_t*)&Qb[ar][8*lg];
        bf16x8_t Qa1 = *(const bf16x8_t*)&Qb[ar][32 + 8*lg];
        f32x4 aKK[4], aQK[4];
#pragma unroll
        for (int nt=0; nt<4; nt++){ aKK[nt]=(f32x4){0,0,0,0}; aQK[nt]=(f32x4){0,0,0,0}; }
#pragma unroll
        for (int nt=0; nt<4; nt++){
            int br = 16*nt + lm;
            bf16x8_t B0 = *(const bf16x8_t*)&Kb[br][8*lg];
            bf16x8_t B1 = *(const bf16x8_t*)&Kb[br][32 + 8*lg];
            aKK[nt] = MF(Ka0, B0, aKK[nt]); aKK[nt] = MF(Ka1, B1, aKK[nt]);
            aQK[nt] = MF(Qa0, B0, aQK[nt]); aQK[nt] = MF(Qa1, B1, aQK[nt]);
        }
#pragma unroll
        for (int r=0; r<4; r++){
            int t = 16*wv + 4*lg + r;
            float lgt = lgS[t];
            float bt = betaS[t];
#pragma unroll
            for (int nt=0; nt<4; nt++){
                int s = 16*nt + lm;
                float ratio = expf(lgt - lgS[s]);
                Lm[t][s] = (s < t) ? bt * ratio * aKK[nt][r] : 0.f;
                Amat_[(long)tile*4096 + t*64 + s] = f2bf((s <= t) ? ratio * aQK[nt][r] : 0.f);
            }
        }
    }
    // init WU = [diag(b*gamma)K | diag(b)V]  (f32, from global)
    {
        int row = tid >> 2, qd = tid & 3;
        long gb = ((long)(b * Tsz + t0 + row) * Hsz + h) << 6;
        float bt = betaS[row];
        float gt = expf(lgS[row]);
        if (qd < 2) {
            int c0 = qd * 32;
            float bg = bt * gt;
#pragma unroll
            for (int j = 0; j < 8; j++) {
                float4 kk = *(const float4*)(k + gb + c0 + 4*j);
                WU[row][c0+4*j+0] = bg*kk.x; WU[row][c0+4*j+1] = bg*kk.y;
                WU[row][c0+4*j+2] = bg*kk.z; WU[row][c0+4*j+3] = bg*kk.w;
            }
        } else {
            int c0 = (qd - 2) * 32;
#pragma unroll
            for (int j = 0; j < 8; j++) {
                float4 vv = *(const float4*)(v + gb + c0 + 4*j);
                WU[row][64+c0+4*j+0] = bt*vv.x; WU[row][64+c0+4*j+1] = bt*vv.y;
                WU[row][64+c0+4*j+2] = bt*vv.z; WU[row][64+c0+4*j+3] = bt*vv.w;
            }
        }
    }
    __syncthreads();

    // forward substitution: (I+L) X = rhs, column-owned, X in registers.
    if (tid < 128) {
        float X[64];
        X[0] = WU[0][tid];
#pragma unroll
        for (int r = 1; r < 64; r++) {
            float a0 = 0.f, a1 = 0.f, a2 = 0.f, a3 = 0.f;
            const float4* L4 = (const float4*)&Lm[r][0];
#pragma unroll
            for (int j = 0; 4*j < r; j++) {
                float4 lv = L4[j];                // wave-uniform broadcast read
                int s = 4*j;
                a0 += lv.x * X[s];
                if (s+1 < r) a1 += lv.y * X[s+1];
                if (s+2 < r) a2 += lv.z * X[s+2];
                if (s+3 < r) a3 += lv.w * X[s+3];
            }
            X[r] = WU[r][tid] - ((a0+a1)+(a2+a3));
        }
#pragma unroll
        for (int r = 0; r < 64; r++) WU[r][tid] = X[r];
    }
    __syncthreads();

    // outputs
    {
        int row = tid >> 2, c0 = (tid & 3) << 4;
        float gt  = expf(lgS[row]);
        float lge = lgS[63];
        long tb = (long)tile * 4096;
#pragma unroll
        for (int c = c0; c < c0 + 16; c++) {
            Wg_[tb + row*64 + c] = f2bf(WU[row][c]);
            U_ [tb + row*64 + c] = WU[row][64 + c];
            Qg_[tb + row*64 + c] = f2bf(gt * bf2f(Qb[row][c]));
            KpT_[tb + row*64 + c] = f2bf(expf(lge - lgS[c]) * bf2f(Kb[c][row]));
        }
        if (tid == 0) gend_[tile] = expf(lge);
    }
}

// ---------------------------------------------------------------- Phase B: sequential chunk scan (dv-parallel)
__global__ __launch_bounds__(64) void chunk_scan_k(
    const u16* __restrict__ Wg_, const u16* __restrict__ Amat_, const u16* __restrict__ Qg_,
    const u16* __restrict__ KpT_, const float* __restrict__ U_, const float* __restrict__ gend_,
    u16* __restrict__ oact)
{
    __shared__ float Sl[16][68];
    __shared__ u16   CT[16][72];
    const int bid = blockIdx.x;
    const int sl = bid >> 5, bh = bid & 31;
    const int b = bh >> 4, h = bh & 15;
    const int dv0 = sl << 4;
    const int lane = threadIdx.x;
    const int lm = lane & 15, lg = lane >> 4;

    f32x4 Sacc0 = {0,0,0,0}, Sacc1 = {0,0,0,0}, Sacc2 = {0,0,0,0}, Sacc3 = {0,0,0,0};

    for (int n = 0; n < 32; n++) {
        const long tb = ((long)(bh*32 + n)) << 12;
#pragma unroll
        for (int r = 0; r < 4; r++) {
            Sl[4*lg + r][ 0 + lm] = Sacc0[r];
            Sl[4*lg + r][16 + lm] = Sacc1[r];
            Sl[4*lg + r][32 + lm] = Sacc2[r];
            Sl[4*lg + r][48 + lm] = Sacc3[r];
        }
        bf16x8_t Wa[4][2], Qa[4][2];
#pragma unroll
        for (int ti = 0; ti < 4; ti++)
#pragma unroll
            for (int kh = 0; kh < 2; kh++) {
                Wa[ti][kh] = *(const bf16x8_t*)(Wg_ + tb + (16*ti + lm)*64 + 32*kh + 8*lg);
                Qa[ti][kh] = *(const bf16x8_t*)(Qg_ + tb + (16*ti + lm)*64 + 32*kh + 8*lg);
            }
        float Uv[4][4];
#pragma unroll
        for (int ti = 0; ti < 4; ti++)
#pragma unroll
            for (int r = 0; r < 4; r++)
                Uv[ti][r] = U_[tb + (16*ti + 4*lg + r)*64 + dv0 + lm];
        const float ge = gend_[bh*32 + n];
        __syncthreads();
        bf16x8_t Shi[2], Slo[2];
#pragma unroll
        for (int kh = 0; kh < 2; kh++) {
            const float* sp = &Sl[lm][32*kh + 8*lg];
            float4 aa = *(const float4*)sp;
            float4 bb = *(const float4*)(sp + 4);
            float xs[8] = {aa.x,aa.y,aa.z,aa.w,bb.x,bb.y,bb.z,bb.w};
#pragma unroll
            for (int j = 0; j < 8; j++) {
                u16 hv = f2bf(xs[j]);
                Shi[kh][j] = (short)hv;
                Slo[kh][j] = (short)f2bf(xs[j] - bf2f(hv));
            }
        }
        f32x4 accP[4];
#pragma unroll
        for (int ti = 0; ti < 4; ti++) {
            accP[ti] = (f32x4){0,0,0,0};
            accP[ti] = MF(Wa[ti][0], Shi[0], accP[ti]);
            accP[ti] = MF(Wa[ti][0], Slo[0], accP[ti]);
            accP[ti] = MF(Wa[ti][1], Shi[1], accP[ti]);
            accP[ti] = MF(Wa[ti][1], Slo[1], accP[ti]);
        }
#pragma unroll
        for (int ti = 0; ti < 4; ti++)
#pragma unroll
            for (int r = 0; r < 4; r++)
                CT[lm][16*ti + 4*lg + r] = f2bf(Uv[ti][r] - accP[ti][r]);
        bf16x8_t Aa[4][2], Kp[4][2];
#pragma unroll
        for (int ti = 0; ti < 4; ti++)
#pragma unroll
            for (int sh = 0; sh < 2; sh++) {
                Aa[ti][sh] = *(const bf16x8_t*)(Amat_ + tb + (16*ti + lm)*64 + 32*sh + 8*lg);
                Kp[ti][sh] = *(const bf16x8_t*)(KpT_  + tb + (16*ti + lm)*64 + 32*sh + 8*lg);
            }
        f32x4 accO[4];
#pragma unroll
        for (int ti = 0; ti < 4; ti++) {
            accO[ti] = (f32x4){0,0,0,0};
            accO[ti] = MF(Qa[ti][0], Shi[0], accO[ti]);
            accO[ti] = MF(Qa[ti][0], Slo[0], accO[ti]);
            accO[ti] = MF(Qa[ti][1], Shi[1], accO[ti]);
            accO[ti] = MF(Qa[ti][1], Slo[1], accO[ti]);
        }
        __syncthreads();
        bf16x8_t CTf[2];
        CTf[0] = *(const bf16x8_t*)&CT[lm][8*lg];
        CTf[1] = *(const bf16x8_t*)&CT[lm][32 + 8*lg];
#pragma unroll
        for (int ti = 0; ti < 4; ti++) {
            accO[ti] = MF(Aa[ti][0], CTf[0], accO[ti]);
            accO[ti] = MF(Aa[ti][1], CTf[1], accO[ti]);
        }
        f32x4 accS0, accS1, accS2, accS3;
        accS0 = (f32x4){ge*Sacc0[0], ge*Sacc0[1], ge*Sacc0[2], ge*Sacc0[3]};
        accS1 = (f32x4){ge*Sacc1[0], ge*Sacc1[1], ge*Sacc1[2], ge*Sacc1[3]};
        accS2 = (f32x4){ge*Sacc2[0], ge*Sacc2[1], ge*Sacc2[2], ge*Sacc2[3]};
        accS3 = (f32x4){ge*Sacc3[0], ge*Sacc3[1], ge*Sacc3[2], ge*Sacc3[3]};
        accS0 = MF(CTf[0], Kp[0][0], accS0); accS0 = MF(CTf[1], Kp[0][1], accS0);
        accS1 = MF(CTf[0], Kp[1][0], accS1); accS1 = MF(CTf[1], Kp[1][1], accS1);
        accS2 = MF(CTf[0], Kp[2][0], accS2); accS2 = MF(CTf[1], Kp[2][1], accS2);
        accS3 = MF(CTf[0], Kp[3][0], accS3); accS3 = MF(CTf[1], Kp[3][1], accS3);
        Sacc0 = accS0; Sacc1 = accS1; Sacc2 = accS2; Sacc3 = accS3;
        const int trow = n*64 + 4*lg;
#pragma unroll
        for (int ti = 0; ti < 4; ti++)
#pragma unroll
            for (int r = 0; r < 4; r++)
                oact[(long)(b*Tsz + trow + 16*ti + r)*1024 + h*64 + dv0 + lm] = f2bf(accO[ti][r]);
        __syncthreads();
    }
}

// ---------------------------------------------------------------- epilogue: +Dp*v, rmsnorm, silu, gate
__global__ __launch_bounds__(256) void epi2_k(
    u16* __restrict__ o, const u16* __restrict__ g, const float* __restrict__ vc,
    const float* __restrict__ Dp, const float* __restrict__ onw)
{
    long row = (long)blockIdx.x * 4 + (threadIdx.x >> 6);
    int lane = threadIdx.x & 63;
    int h = (int)(row & 15);
    long idx = (row << 6) + lane;
    float ov = bf2f(o[idx]) + Dp[h] * vc[idx];
    float gv = bf2f(g[idx]);
    float ss = ov * ov;
#pragma unroll
    for (int off = 1; off < 64; off <<= 1) ss += __shfl_xor(ss, off);
    float r   = rsqrtf(ss * (1.f / 64.f) + 1e-6f);
    float on  = onw[lane] * (ov * r);
    float sil = on / (1.f + expf(-on));
    o[idx] = f2bf(gv * sil);
}

// ---------------------------------------------------------------- host launch
extern "C" void kernel_launch(void* const* d_in, const int* in_sizes, int n_in,
                              void* d_out, int out_size, void* d_ws, size_t ws_size,
                              hipStream_t stream)
{
    const float* x    = (const float*)d_in[0];
    const float* Wq   = (const float*)d_in[1];
    const float* Wk   = (const float*)d_in[2];
    const float* Wv   = (const float*)d_in[3];
    const float* Wg   = (const float*)d_in[4];
    const float* Wo   = (const float*)d_in[5];
    const float* Wb   = (const float*)d_in[6];
    const float* bb   = (const float*)d_in[7];
    const float* Wgk  = (const float*)d_in[8];
    const float* bgk  = (const float*)d_in[9];
    const float* cqw  = (const float*)d_in[10];
    const float* cqb  = (const float*)d_in[11];
    const float* ckw  = (const float*)d_in[12];
    const float* ckb  = (const float*)d_in[13];
    const float* cvw  = (const float*)d_in[14];
    const float* cvb  = (const float*)d_in[15];
    const float* A_log= (const float*)d_in[16];
    const float* Dp   = (const float*)d_in[17];
    const float* dtb  = (const float*)d_in[18];
    const float* onw  = (const float*)d_in[19];
    float* out = (float*)d_out;

    char* p = (char*)d_ws;
    auto alloc = [&](size_t bytes) -> char* {
        char* r = p; p += (bytes + 255) & ~(size_t)255; return r;
    };
    const size_t NBT = (size_t)BT * Csz;          // 4M elements
    const size_t NTILE = (size_t)32 * 32;         // 1024 chunk tiles
    u16*   xbf   = (u16*)  alloc(NBT * 2);
    u16*   wcat  = (u16*)  alloc((size_t)5 * Csz * Csz * 2);  // [Wq;Wk;Wv;Wg;Wo] bf16, contiguous
    u16*   qkvg  = (u16*)  alloc((size_t)4 * NBT * 2);        // qpre|kpre|vpre|gbf contiguous
    float* qconv = (float*)alloc(NBT * 4);
    float* kconv = (float*)alloc(NBT * 4);
    float* ctab  = (float*)alloc((size_t)Tsz * 16 * 4);
    float* stab  = (float*)alloc((size_t)Tsz * 16 * 4);
    float* lalpha= (float*)alloc((size_t)BT * Hsz * 4);
    float* beta  = (float*)alloc((size_t)BT * Hsz * 4);
    u16*   Wg_t  = (u16*)  alloc(NTILE * 4096 * 2);
    u16*   Amat_t= (u16*)  alloc(NTILE * 4096 * 2);
    u16*   Qg_t  = (u16*)  alloc(NTILE * 4096 * 2);
    u16*   KpT_t = (u16*)  alloc(NTILE * 4096 * 2);
    float* U_t   = (float*)alloc(NTILE * 4096 * 4);
    float* gend_t= (float*)alloc(NTILE * 4);

    u16* Wobf = wcat + (size_t)4 * Csz * Csz;
    u16* qpre = qkvg;
    u16* vpre = qkvg + 2 * NBT;
    u16* gbf  = qkvg + 3 * NBT;
    // overlays (stream-ordered reuse of dead buffers):
    float* vconv = (float*)qpre;   // 16MB over qpre+kpre (dead after conv_q/conv_k LAUNCH completes)
    u16*   oact  = (u16*)vpre;     // 8MB over vpre (dead after conv_v)

    // 1. rope tables
    rope_tables_k<<<(Tsz * 16 + 255) / 256, 256, 0, stream>>>(ctab, stab);

    // 2. f32 -> bf16 conversions (x + 5 weight mats)
    cvt_f32_bf16_k<<<(int)(NBT / 4 + 255) / 256, 256, 0, stream>>>(x, xbf, (int)NBT);
    cvt_w_k<<<dim3(Csz * Csz / 4 / 256, 5), 256, 0, stream>>>(Wq, Wk, Wv, Wg, Wo, wcat);

    // 3. fused QKVG projection: M=4096, N=4096 over contiguous weights, split-store
    gemm_bf16_nt<<<32 * 32, 256, 0, stream>>>(xbf, wcat, nullptr, qkvg, 32, (long)NBT, Csz);

    // 4. depthwise conv + silu: q,k first; v in a SEPARATE launch (overlay ordering)
    conv_silu_k<<<dim3(Bsz * (Tsz / 64), Csz / 256, 2), 256, 0, stream>>>(
        qkvg, 0, cqw, cqb, ckw, ckb, cvw, cvb, qconv, kconv, vconv);
    conv_silu_k<<<dim3(Bsz * (Tsz / 64), Csz / 256, 1), 256, 0, stream>>>(
        qkvg, 2, cqw, cqb, ckw, ckb, cvw, cvb, qconv, kconv, vconv);

    // 5. rope + l2norm, in place on q and k (fused)
    rope_l2norm_k<<<dim3((Bsz * Tsz * Hsz) / 4, 2), 256, 0, stream>>>(qconv, kconv, ctab, stab);

    // 6. beta / log-alpha
    ab_k<<<BT, 256, 0, stream>>>(x, Wb, bb, Wgk, bgk, A_log, dtb, lalpha, beta);

    // 7a. chunk precompute (parallel over 1024 tiles)
    chunk_prep_k<<<1024, 256, 0, stream>>>(qconv, kconv, vconv, lalpha, beta,
                                           Wg_t, Amat_t, Qg_t, KpT_t, U_t, gend_t);

    // 7b. sequential chunk scan: 4 dv-slices x 32 (b,h), 1 wave each
    chunk_scan_k<<<128, 64, 0, stream>>>(Wg_t, Amat_t, Qg_t, KpT_t, U_t, gend_t, oact);

    // 8. epilogue: D-skip + rmsnorm + silu + gate, in place on oact
    epi2_k<<<(BT * Hsz) / 4, 256, 0, stream>>>(oact, gbf, vconv, Dp, onw);

    // 9. output projection (f32 -> d_out)
    gemm_bf16_nt<<<32 * 8, 256, 0, stream>>>(oact, Wobf, out, nullptr, 32, 0L, Csz);

    (void)in_sizes; (void)n_in; (void)out_size; (void)ws_size;
}